// Round 6
// baseline (1393.813 us; speedup 1.0000x reference)
//
#include <hip/hip_runtime.h>
#include <cstddef>

typedef __attribute__((ext_vector_type(8))) short bf16x8;
typedef __attribute__((ext_vector_type(4))) float f32x4;
typedef __attribute__((ext_vector_type(4))) unsigned short u16x4;
typedef __attribute__((ext_vector_type(8))) unsigned short u16x8;

namespace {
constexpr int B_ = 3, S_ = 4096, H_ = 1024, NH_ = 32;
constexpr int SEG1 = 1, SEG2 = 2049;
constexpr int NQ1 = 2048, NK1 = 2047, NQ2 = 2047, NK2 = 2048;
constexpr float SCALE = 0.17677669529663687f;              // 1/sqrt(32)
constexpr float LOG2E = 1.4426950408889634f;
constexpr float QSC   = SCALE * LOG2E;                     // folded into Wq/bq

// workspace byte offsets (all 16B aligned)
constexpr size_t oXb = 0;                                   // 12288*1024 bf16
constexpr size_t oWb = oXb + (size_t)12288 * 1024 * 2;      // 2048*1024 bf16
constexpr size_t oBB = oWb + (size_t)2048 * 1024 * 2;       // 2048 f32
constexpr size_t oQH = oBB + (size_t)2048 * 4;              // 6*32*2048*32 bf16
constexpr size_t oKH = oQH + (size_t)6 * 32 * 2048 * 32 * 2;
constexpr size_t oNL = oKH + (size_t)6 * 32 * 2048 * 32 * 2;  // negL 6*2048 f32
constexpr size_t oCS = oNL + (size_t)6 * 2048 * 4;          // 6*32*2048 f32
constexpr size_t oU  = oCS + (size_t)6 * 32 * 2048 * 4;     // 6*32*1024 f32
constexpr size_t oMv = oU  + (size_t)6 * 32 * 1024 * 4;     // 6*1024 f32
}

#if __has_builtin(__builtin_amdgcn_exp2f)
#define EXP2(x) __builtin_amdgcn_exp2f(x)
#else
#define EXP2(x) exp2f(x)
#endif
#if __has_builtin(__builtin_amdgcn_logf)
#define LOG2(x) __builtin_amdgcn_logf(x)
#else
#define LOG2(x) log2f(x)
#endif

__device__ __forceinline__ unsigned short f2bf(float f) {
    unsigned u = __float_as_uint(f);
    u += 0x7FFF + ((u >> 16) & 1);   // RTNE
    return (unsigned short)(u >> 16);
}
__device__ __forceinline__ float bf2f(unsigned short u) {
    return __uint_as_float((unsigned)u << 16);
}
__device__ __forceinline__ void gl16(const unsigned short* gp, unsigned short* lp) {
    __builtin_amdgcn_global_load_lds(
        (const __attribute__((address_space(1))) unsigned int*)gp,
        (__attribute__((address_space(3))) unsigned int*)lp, 16, 0, 0);
}

// ---------------------------------------------------------------------------
__global__ __launch_bounds__(256) void conv_x(const float* __restrict__ X,
                                              unsigned short* __restrict__ Xb)
{
    const size_t i4 = (size_t)blockIdx.x * 256 + threadIdx.x;
    const float4 v = *(const float4*)&X[i4 * 4];
    u16x4 o;
    o[0] = f2bf(v.x); o[1] = f2bf(v.y); o[2] = f2bf(v.z); o[3] = f2bf(v.w);
    *(u16x4*)&Xb[i4 * 4] = o;
}

// pack [QSC*Wq ; Wk] -> bf16, [QSC*bq ; bk] -> f32; also zero pad rows of QH/KH
__global__ __launch_bounds__(256) void conv_w(const float* __restrict__ Wq,
                                              const float* __restrict__ bq,
                                              const float* __restrict__ Wk,
                                              const float* __restrict__ bk,
                                              unsigned short* __restrict__ Wb,
                                              float* __restrict__ bb,
                                              unsigned short* __restrict__ QH,
                                              unsigned short* __restrict__ KH)
{
    const int i4 = blockIdx.x * 256 + threadIdx.x;
    const int base = i4 * 4;
    const bool isQ = base < (1 << 20);
    const float sc = isQ ? QSC : 1.f;
    const float* src = isQ ? &Wq[base] : &Wk[base - (1 << 20)];
    const float4 v = *(const float4*)src;
    u16x4 o;
    o[0] = f2bf(v.x * sc); o[1] = f2bf(v.y * sc);
    o[2] = f2bf(v.z * sc); o[3] = f2bf(v.w * sc);
    *(u16x4*)&Wb[base] = o;
    if (base < 2048) {
#pragma unroll
        for (int c = 0; c < 4; ++c) {
            const int j = base + c;
            bb[j] = (j < 1024) ? QSC * bq[j] : bk[j - 1024];
        }
    }
    if (i4 < 3072) {   // zero pad rows (idx 2047 of mha1-Q and mha0-K panels)
        const int b = i4 >> 10, rem = i4 & 1023, h = rem >> 5, c = rem & 31;
        QH[(((size_t)(b * 2 + 1) * NH_ + h) * 2048 + 2047) * 32 + c] = 0;
        KH[(((size_t)(b * 2 + 0) * NH_ + h) * 2048 + 2047) * 32 + c] = 0;
    }
}

// ---------------------------------------------------------------------------
// Fused Q|K projection -> head-major scatter.  A-operand = W (channels on the
// D row dim), B-operand = X (rows on the D col dim) so each lane owns 4
// CONSECUTIVE dk channels -> vectorized 8B scatter stores.
// ---------------------------------------------------------------------------
__global__ __launch_bounds__(256) void proj_mfma(const unsigned short* __restrict__ Xb,
                                                 const unsigned short* __restrict__ Wb,
                                                 const float* __restrict__ bb,
                                                 unsigned short* __restrict__ QH,
                                                 unsigned short* __restrict__ KH)
{
    __shared__ unsigned short ldsX[2][4096];   // [buf][128 rows * 32 (=BK)]
    __shared__ unsigned short ldsW[2][4096];
    const int tid = threadIdx.x;
    const int lane = tid & 63, w = tid >> 6;
    const int m0 = blockIdx.x * 128;   // x-rows
    const int n0 = blockIdx.y * 128;   // output channels (Q: 0..1023, K: 1024..2047)
    const int cr = (w >> 1) * 64;      // channel half owned by this wave
    const int xc = (w & 1) * 64;       // xrow half owned by this wave

    // staging: lane -> row (lane>>2), granule pre-swizzled g ^ ((row>>1)&3)
    const int co = ((lane & 3) ^ ((lane >> 3) & 3)) * 8;
    const unsigned short* gX = Xb + (size_t)(m0 + 32 * w + (lane >> 2)) * 1024 + co;
    const unsigned short* gW = Wb + (size_t)(n0 + 32 * w + (lane >> 2)) * 1024 + co;

#define STAGE(K0, BUF) do { \
    gl16(gX + (K0),             &ldsX[BUF][(32 * w) * 32]); \
    gl16(gX + (K0) + 16 * 1024, &ldsX[BUF][(32 * w + 16) * 32]); \
    gl16(gW + (K0),             &ldsW[BUF][(32 * w) * 32]); \
    gl16(gW + (K0) + 16 * 1024, &ldsW[BUF][(32 * w + 16) * 32]); \
} while (0)

    // fragment read offsets (same XOR on the read side; row+16 keeps same XOR)
    const int lr = lane & 15, lg = lane >> 4;
    const int mrW = cr + lr, mrX = xc + lr;
    const int oW = mrW * 32 + ((lg ^ ((mrW >> 1) & 3)) * 8);
    const int oX = mrX * 32 + ((lg ^ ((mrX >> 1) & 3)) * 8);

    f32x4 acc[4][4] = {};
    STAGE(0, 0);
    asm volatile("s_waitcnt vmcnt(0)" ::: "memory");
    __syncthreads();

    for (int kt = 0; kt < 32; ++kt) {
        const int buf = kt & 1;
        if (kt < 31) STAGE((kt + 1) * 32, buf ^ 1);
        bf16x8 wf[4], xf[4];
#pragma unroll
        for (int i = 0; i < 4; ++i) wf[i] = *(const bf16x8*)&ldsW[buf][oW + i * 512];
#pragma unroll
        for (int j = 0; j < 4; ++j) xf[j] = *(const bf16x8*)&ldsX[buf][oX + j * 512];
#pragma unroll
        for (int i = 0; i < 4; ++i)
#pragma unroll
            for (int j = 0; j < 4; ++j)
                acc[i][j] = __builtin_amdgcn_mfma_f32_16x16x32_bf16(wf[i], xf[j], acc[i][j], 0, 0, 0);
        asm volatile("s_waitcnt vmcnt(0)" ::: "memory");
        __syncthreads();
    }
#undef STAGE

    // epilogue: head-major scatter, 8B vector stores.
    const bool sideK = (n0 >= 1024);
    unsigned short* dst = sideK ? KH : QH;

    int rowoff[4];   // per xrow fragment j (row = lane&15 of D)
#pragma unroll
    for (int j = 0; j < 4; ++j) {
        const int g = m0 + xc + 16 * j + lr;
        const int b = g >> 12, rr = g & 4095;
        int v = -1;
        if (rr >= 2049) {
            const int seg = b * 2 + (sideK ? 0 : 1);
            v = seg * (NH_ * 2048 * 32) + (rr - 2049) * 32;
        } else if (rr >= 1) {
            const int seg = b * 2 + (sideK ? 1 : 0);
            v = seg * (NH_ * 2048 * 32) + (rr - 1) * 32;
        }
        rowoff[j] = v;
    }

    int coloff[4]; f32x4 bias4[4];   // per channel fragment i (4 consec chans)
#pragma unroll
    for (int i = 0; i < 4; ++i) {
        const int c = n0 + cr + 16 * i + lg * 4;
        const int local = c - (sideK ? 1024 : 0);
        coloff[i] = (local >> 5) * (2048 * 32) + (local & 31);
        bias4[i] = *(const f32x4*)&bb[c];
    }

#pragma unroll
    for (int j = 0; j < 4; ++j) {
        if (rowoff[j] < 0) continue;
#pragma unroll
        for (int i = 0; i < 4; ++i) {
            u16x4 o;
#pragma unroll
            for (int r = 0; r < 4; ++r) o[r] = f2bf(acc[i][j][r] + bias4[i][r]);
            *(u16x4*)&dst[(size_t)rowoff[j] + coloff[i]] = o;
        }
    }
}

// ---------------------------------------------------------------------------
// Pass 1: negL[bm][q] = -log2( sum_k exp2(s2[q][k]) ), s2 = log2-domain score.
// grid (8, 32 heads, 6 bm); each wave owns 64 q rows (4 A-frags), streams K
// with 1-deep register prefetch.
// ---------------------------------------------------------------------------
__global__ __launch_bounds__(256) void zpass(const unsigned short* __restrict__ QH,
                                             const unsigned short* __restrict__ KH,
                                             float* __restrict__ NL)
{
    const int tid = threadIdx.x, lane = tid & 63, w = tid >> 6;
    const int bm = blockIdx.z, mha = bm & 1;
    const int h = blockIdx.y;
    const int nq = mha ? NQ2 : NQ1, nk = mha ? NK2 : NK1;
    const size_t panel = ((size_t)bm * NH_ + h) * 2048 * 32;
    const int lr = lane & 15, lg = lane >> 4;
    const int q0 = blockIdx.x * 256 + w * 64;
    const f32x4 zero = {0.f, 0.f, 0.f, 0.f};

    const unsigned short* Qp = QH + panel + (size_t)(q0 + lr) * 32 + lg * 8;
    const unsigned short* Kp = KH + panel + (size_t)lr * 32 + lg * 8;

    bf16x8 a[4];
#pragma unroll
    for (int i = 0; i < 4; ++i) a[i] = *(const bf16x8*)(Qp + i * 16 * 32);

    bf16x8 kb = *(const bf16x8*)(Kp);
    float z[4][4] = {};
#pragma unroll 2
    for (int kt = 0; kt < 127; ++kt) {
        const bf16x8 kn = *(const bf16x8*)(Kp + (size_t)(kt + 1) * 512);
#pragma unroll
        for (int i = 0; i < 4; ++i) {
            const f32x4 d = __builtin_amdgcn_mfma_f32_16x16x32_bf16(a[i], kb, zero, 0, 0, 0);
#pragma unroll
            for (int r = 0; r < 4; ++r) z[i][r] += EXP2(d[r]);
        }
        kb = kn;
    }
    {   // tail k-tile (kt=127, already in kb) with column mask
        const float m = (2032 + lr < nk) ? 1.f : 0.f;
#pragma unroll
        for (int i = 0; i < 4; ++i) {
            const f32x4 d = __builtin_amdgcn_mfma_f32_16x16x32_bf16(a[i], kb, zero, 0, 0, 0);
#pragma unroll
            for (int r = 0; r < 4; ++r) z[i][r] += m * EXP2(d[r]);
        }
    }

#pragma unroll
    for (int i = 0; i < 4; ++i) {
#pragma unroll
        for (int r = 0; r < 4; ++r) {
            float v = z[i][r];
            v += __shfl_xor(v, 1, 64);
            v += __shfl_xor(v, 2, 64);
            v += __shfl_xor(v, 4, 64);
            v += __shfl_xor(v, 8, 64);
            z[i][r] = v;
        }
        if (lr == 0) {
            const int qb = q0 + i * 16 + lg * 4;
            f32x4 o;
#pragma unroll
            for (int r = 0; r < 4; ++r)
                o[r] = (qb + r < nq) ? -LOG2(z[i][r]) : -1e30f;  // -inf masks pad q
            *(f32x4*)&NL[(size_t)bm * 2048 + qb] = o;
        }
    }
}

// ---------------------------------------------------------------------------
// Pass 2: CS[bm][h][k] = sum_q exp2(s2[q][k] + negL[q]).  negL rides in the
// MFMA accumulator; 1-deep register prefetch of (ai, cv).
// ---------------------------------------------------------------------------
__global__ __launch_bounds__(256) void colsum(const unsigned short* __restrict__ QH,
                                              const unsigned short* __restrict__ KH,
                                              const float* __restrict__ NL,
                                              float* __restrict__ CS)
{
    const int tid = threadIdx.x, lane = tid & 63, w = tid >> 6;
    const int bm = blockIdx.z, mha = bm & 1;
    const int h = blockIdx.y;
    const int nk = mha ? NK2 : NK1;
    const size_t panel = ((size_t)bm * NH_ + h) * 2048 * 32;
    const int lr = lane & 15, lg = lane >> 4;
    const int kc = blockIdx.x * 256 + w * 64;

    const unsigned short* Kp = KH + panel + (size_t)(kc + lr) * 32 + lg * 8;
    const unsigned short* Qp = QH + panel + (size_t)lr * 32 + lg * 8;
    const float* zp = NL + (size_t)bm * 2048 + lg * 4;

    bf16x8 kb[4];
#pragma unroll
    for (int j = 0; j < 4; ++j) kb[j] = *(const bf16x8*)(Kp + j * 16 * 32);

    bf16x8 ai = *(const bf16x8*)(Qp);
    f32x4 cv = *(const f32x4*)(zp);
    float cacc[4] = {};
#pragma unroll 2
    for (int qt = 0; qt < 128; ++qt) {
        bf16x8 an; f32x4 cn;
        if (qt < 127) {
            an = *(const bf16x8*)(Qp + (size_t)(qt + 1) * 512);
            cn = *(const f32x4*)(zp + (qt + 1) * 16);
        }
        const f32x4 d0 = __builtin_amdgcn_mfma_f32_16x16x32_bf16(ai, kb[0], cv, 0, 0, 0);
        const f32x4 d1 = __builtin_amdgcn_mfma_f32_16x16x32_bf16(ai, kb[1], cv, 0, 0, 0);
        const f32x4 d2 = __builtin_amdgcn_mfma_f32_16x16x32_bf16(ai, kb[2], cv, 0, 0, 0);
        const f32x4 d3 = __builtin_amdgcn_mfma_f32_16x16x32_bf16(ai, kb[3], cv, 0, 0, 0);
#pragma unroll
        for (int r = 0; r < 4; ++r) cacc[0] += EXP2(d0[r]);
#pragma unroll
        for (int r = 0; r < 4; ++r) cacc[1] += EXP2(d1[r]);
#pragma unroll
        for (int r = 0; r < 4; ++r) cacc[2] += EXP2(d2[r]);
#pragma unroll
        for (int r = 0; r < 4; ++r) cacc[3] += EXP2(d3[r]);
        ai = an; cv = cn;
    }

#pragma unroll
    for (int j = 0; j < 4; ++j) {
        float v = cacc[j];
        v += __shfl_xor(v, 16, 64);
        v += __shfl_xor(v, 32, 64);
        const int col = kc + 16 * j + lr;
        if (lane < 16 && col < nk)
            CS[((size_t)bm * NH_ + h) * 2048 + col] = v;
    }
}

// ---------------------------------------------------------------------------
// Pass C: u[bm][h][c] = sum_k CS[bm][h][k] * Xb[kbase+k][c]   (bf16 X)
// grid (32 ktiles of 64, 4 headgroups, 6 bm)
// ---------------------------------------------------------------------------
__global__ __launch_bounds__(256) void colsum_x(
    const unsigned short* __restrict__ Xb, const float* __restrict__ CS,
    float* __restrict__ U)
{
    __shared__ float sl[8][64];
    const int tid = threadIdx.x;
    const int bm = blockIdx.z;
    const int b = bm >> 1, mha = bm & 1;
    const int kbase = mha ? SEG1 : SEG2;
    const int nk = mha ? NK2 : NK1;
    const int kt = blockIdx.x * 64;
    const int hg = blockIdx.y * 8;

    for (int idx = tid; idx < 8 * 64; idx += 256) {
        const int hh = idx >> 6, kk = idx & 63;
        const int k = kt + kk;
        sl[hh][kk] = (k < nk) ? CS[((size_t)bm * NH_ + hg + hh) * 2048 + k] : 0.f;
    }
    __syncthreads();

    float acc[8][4] = {};
    const int c4 = tid * 4;
    for (int kk = 0; kk < 64; ++kk) {
        const int k = kt + kk;
        if (k >= nk) break;   // uniform across block
        const u16x4 xv = *(const u16x4*)&Xb[((size_t)b * S_ + kbase + k) * H_ + c4];
        const float x0 = bf2f(xv[0]), x1 = bf2f(xv[1]), x2 = bf2f(xv[2]), x3 = bf2f(xv[3]);
#pragma unroll
        for (int hh = 0; hh < 8; ++hh) {
            const float sv = sl[hh][kk];
            acc[hh][0] += sv * x0; acc[hh][1] += sv * x1;
            acc[hh][2] += sv * x2; acc[hh][3] += sv * x3;
        }
    }
#pragma unroll
    for (int hh = 0; hh < 8; ++hh)
#pragma unroll
        for (int c = 0; c < 4; ++c)
            atomicAdd(&U[((size_t)bm * NH_ + hg + hh) * H_ + c4 + c], acc[hh][c]);
}

// ---------------------------------------------------------------------------
__global__ __launch_bounds__(256) void compute_m(
    const float* __restrict__ U, const float* __restrict__ Wv,
    const float* __restrict__ bv, float* __restrict__ Mvec)
{
    const int bm = blockIdx.y;
    const int mha = bm & 1;
    const float invnq = 1.f / (float)(mha ? NQ2 : NQ1);
    const int o = blockIdx.x * 256 + threadIdx.x;
    const int hh = o >> 5;
    const float* u = &U[((size_t)bm * NH_ + hh) * H_];
    const float* w = &Wv[(size_t)o * H_];
    float acc = 0.f;
    for (int in = 0; in < H_; in += 4) {
        const float4 uv = *(const float4*)&u[in];
        const float4 wv = *(const float4*)&w[in];
        acc += uv.x * wv.x + uv.y * wv.y + uv.z * wv.z + uv.w * wv.w;
    }
    Mvec[(size_t)bm * H_ + o] = acc * invnq + bv[o];
}

__global__ __launch_bounds__(256) void final_out(
    const float* __restrict__ Mvec, const float* __restrict__ Wo,
    const float* __restrict__ bo, float* __restrict__ out)
{
    const int bm = blockIdx.y;
    const int b = bm >> 1, mha = bm & 1;
    const int o = blockIdx.x * 256 + threadIdx.x;
    const float* mv = &Mvec[(size_t)bm * H_];
    const float* w = &Wo[(size_t)o * H_];
    float acc = 0.f;
    for (int in = 0; in < H_; in += 4) {
        const float4 mvv = *(const float4*)&mv[in];
        const float4 wv = *(const float4*)&w[in];
        acc += mvv.x * wv.x + mvv.y * wv.y + mvv.z * wv.z + mvv.w * wv.w;
    }
    out[(size_t)b * 2048 + mha * 1024 + o] = acc + bo[o];
}

// ---------------------------------------------------------------------------
extern "C" void kernel_launch(void* const* d_in, const int* in_sizes, int n_in,
                              void* d_out, int out_size, void* d_ws, size_t ws_size,
                              hipStream_t stream)
{
    const float* hidden = (const float*)d_in[0];
    const float* Wq = (const float*)d_in[7];
    const float* bq = (const float*)d_in[8];
    const float* Wk = (const float*)d_in[9];
    const float* bk = (const float*)d_in[10];
    const float* Wv = (const float*)d_in[11];
    const float* bv = (const float*)d_in[12];
    const float* Wo = (const float*)d_in[13];
    const float* bo = (const float*)d_in[14];
    float* out = (float*)d_out;
    char* ws = (char*)d_ws;

    unsigned short* Xb  = (unsigned short*)(ws + oXb);
    unsigned short* Wb  = (unsigned short*)(ws + oWb);
    float* bb           = (float*)(ws + oBB);
    unsigned short* QHp = (unsigned short*)(ws + oQH);
    unsigned short* KHp = (unsigned short*)(ws + oKH);
    float* NL           = (float*)(ws + oNL);
    float* CS           = (float*)(ws + oCS);
    float* U            = (float*)(ws + oU);
    float* Mv           = (float*)(ws + oMv);

    hipMemsetAsync(U, 0, (size_t)6 * NH_ * H_ * sizeof(float), stream);

    const dim3 blk(256);
    conv_x<<<12288, blk, 0, stream>>>(hidden, Xb);
    conv_w<<<2048, blk, 0, stream>>>(Wq, bq, Wk, bk, Wb, bb, QHp, KHp);
    proj_mfma<<<dim3(96, 16), blk, 0, stream>>>(Xb, Wb, bb, QHp, KHp);
    zpass<<<dim3(8, 32, 6), blk, 0, stream>>>(QHp, KHp, NL);
    colsum<<<dim3(8, 32, 6), blk, 0, stream>>>(QHp, KHp, NL, CS);
    colsum_x<<<dim3(32, 4, 6), blk, 0, stream>>>(Xb, CS, U);
    compute_m<<<dim3(4, 6), blk, 0, stream>>>(U, Wv, bv, Mv);
    final_out<<<dim3(4, 6), blk, 0, stream>>>(Mv, Wo, bo, out);
}

// Round 7
// 511.816 us; speedup vs baseline: 2.7233x; 2.7233x over previous
//
#include <hip/hip_runtime.h>
#include <cstddef>

typedef __attribute__((ext_vector_type(8))) short bf16x8;
typedef __attribute__((ext_vector_type(4))) float f32x4;
typedef __attribute__((ext_vector_type(4))) unsigned short u16x4;
typedef __attribute__((ext_vector_type(8))) unsigned short u16x8;

namespace {
constexpr int B_ = 3, S_ = 4096, H_ = 1024, NH_ = 32;
constexpr int SEG1 = 1, SEG2 = 2049;
constexpr int NQ1 = 2048, NK1 = 2047, NQ2 = 2047, NK2 = 2048;
constexpr float SCALE = 0.17677669529663687f;              // 1/sqrt(32)
constexpr float LOG2E = 1.4426950408889634f;
constexpr float QSC   = SCALE * LOG2E;                     // folded into Wq/bq

// workspace byte offsets (all 16B aligned)
constexpr size_t oXb = 0;                                   // 12288*1024 bf16
constexpr size_t oWb = oXb + (size_t)12288 * 1024 * 2;      // 2048*1024 bf16
constexpr size_t oBB = oWb + (size_t)2048 * 1024 * 2;       // 2048 f32
constexpr size_t oQH = oBB + (size_t)2048 * 4;              // 6*32*2048*32 bf16
constexpr size_t oKH = oQH + (size_t)6 * 32 * 2048 * 32 * 2;
constexpr size_t oNL = oKH + (size_t)6 * 32 * 2048 * 32 * 2;  // negL 6*2048 f32
constexpr size_t oCS = oNL + (size_t)6 * 2048 * 4;          // 6*32*2048 f32
constexpr size_t oU  = oCS + (size_t)6 * 32 * 2048 * 4;     // 6*32*1024 f32
constexpr size_t oMv = oU  + (size_t)6 * 32 * 1024 * 4;     // 6*1024 f32
}

#if __has_builtin(__builtin_amdgcn_exp2f)
#define EXP2(x) __builtin_amdgcn_exp2f(x)
#else
#define EXP2(x) exp2f(x)
#endif
#if __has_builtin(__builtin_amdgcn_logf)
#define LOG2(x) __builtin_amdgcn_logf(x)
#else
#define LOG2(x) log2f(x)
#endif

__device__ __forceinline__ unsigned short f2bf(float f) {
    unsigned u = __float_as_uint(f);
    u += 0x7FFF + ((u >> 16) & 1);   // RTNE
    return (unsigned short)(u >> 16);
}
__device__ __forceinline__ float bf2f(unsigned short u) {
    return __uint_as_float((unsigned)u << 16);
}
__device__ __forceinline__ void gl16(const unsigned short* gp, unsigned short* lp) {
    __builtin_amdgcn_global_load_lds(
        (const __attribute__((address_space(1))) unsigned int*)gp,
        (__attribute__((address_space(3))) unsigned int*)lp, 16, 0, 0);
}

// ---------------------------------------------------------------------------
__global__ __launch_bounds__(256) void conv_x(const float* __restrict__ X,
                                              unsigned short* __restrict__ Xb)
{
    const size_t i4 = (size_t)blockIdx.x * 256 + threadIdx.x;
    const float4 v = *(const float4*)&X[i4 * 4];
    u16x4 o;
    o[0] = f2bf(v.x); o[1] = f2bf(v.y); o[2] = f2bf(v.z); o[3] = f2bf(v.w);
    *(u16x4*)&Xb[i4 * 4] = o;
}

// pack [QSC*Wq ; Wk] -> bf16, [QSC*bq ; bk] -> f32; also zero pad rows of QH/KH
__global__ __launch_bounds__(256) void conv_w(const float* __restrict__ Wq,
                                              const float* __restrict__ bq,
                                              const float* __restrict__ Wk,
                                              const float* __restrict__ bk,
                                              unsigned short* __restrict__ Wb,
                                              float* __restrict__ bb,
                                              unsigned short* __restrict__ QH,
                                              unsigned short* __restrict__ KH)
{
    const int i4 = blockIdx.x * 256 + threadIdx.x;
    const int base = i4 * 4;
    const bool isQ = base < (1 << 20);
    const float sc = isQ ? QSC : 1.f;
    const float* src = isQ ? &Wq[base] : &Wk[base - (1 << 20)];
    const float4 v = *(const float4*)src;
    u16x4 o;
    o[0] = f2bf(v.x * sc); o[1] = f2bf(v.y * sc);
    o[2] = f2bf(v.z * sc); o[3] = f2bf(v.w * sc);
    *(u16x4*)&Wb[base] = o;
    if (base < 2048) {
#pragma unroll
        for (int c = 0; c < 4; ++c) {
            const int j = base + c;
            bb[j] = (j < 1024) ? QSC * bq[j] : bk[j - 1024];
        }
    }
    if (i4 < 3072) {   // zero pad rows (idx 2047 of mha1-Q and mha0-K panels)
        const int b = i4 >> 10, rem = i4 & 1023, h = rem >> 5, c = rem & 31;
        QH[(((size_t)(b * 2 + 1) * NH_ + h) * 2048 + 2047) * 32 + c] = 0;
        KH[(((size_t)(b * 2 + 0) * NH_ + h) * 2048 + 2047) * 32 + c] = 0;
    }
}

// ---------------------------------------------------------------------------
// Fused Q|K projection -> head-major scatter.  A-operand = W (channels on the
// D row dim), B-operand = X (rows on the D col dim) so each lane owns 4
// CONSECUTIVE dk channels -> vectorized 8B scatter stores.
// ---------------------------------------------------------------------------
__global__ __launch_bounds__(256) void proj_mfma(const unsigned short* __restrict__ Xb,
                                                 const unsigned short* __restrict__ Wb,
                                                 const float* __restrict__ bb,
                                                 unsigned short* __restrict__ QH,
                                                 unsigned short* __restrict__ KH)
{
    __shared__ unsigned short ldsX[2][4096];   // [buf][128 rows * 32 (=BK)]
    __shared__ unsigned short ldsW[2][4096];
    const int tid = threadIdx.x;
    const int lane = tid & 63, w = tid >> 6;
    const int m0 = blockIdx.x * 128;   // x-rows
    const int n0 = blockIdx.y * 128;   // output channels (Q: 0..1023, K: 1024..2047)
    const int cr = (w >> 1) * 64;      // channel half owned by this wave
    const int xc = (w & 1) * 64;       // xrow half owned by this wave

    // staging: lane -> row (lane>>2), granule pre-swizzled g ^ ((row>>1)&3)
    const int co = ((lane & 3) ^ ((lane >> 3) & 3)) * 8;
    const unsigned short* gX = Xb + (size_t)(m0 + 32 * w + (lane >> 2)) * 1024 + co;
    const unsigned short* gW = Wb + (size_t)(n0 + 32 * w + (lane >> 2)) * 1024 + co;

#define STAGE(K0, BUF) do { \
    gl16(gX + (K0),             &ldsX[BUF][(32 * w) * 32]); \
    gl16(gX + (K0) + 16 * 1024, &ldsX[BUF][(32 * w + 16) * 32]); \
    gl16(gW + (K0),             &ldsW[BUF][(32 * w) * 32]); \
    gl16(gW + (K0) + 16 * 1024, &ldsW[BUF][(32 * w + 16) * 32]); \
} while (0)

    // fragment read offsets (same XOR on the read side; row+16 keeps same XOR)
    const int lr = lane & 15, lg = lane >> 4;
    const int mrW = cr + lr, mrX = xc + lr;
    const int oW = mrW * 32 + ((lg ^ ((mrW >> 1) & 3)) * 8);
    const int oX = mrX * 32 + ((lg ^ ((mrX >> 1) & 3)) * 8);

    f32x4 acc[4][4] = {};
    STAGE(0, 0);
    asm volatile("s_waitcnt vmcnt(0)" ::: "memory");
    __syncthreads();

    for (int kt = 0; kt < 32; ++kt) {
        const int buf = kt & 1;
        if (kt < 31) STAGE((kt + 1) * 32, buf ^ 1);
        bf16x8 wf[4], xf[4];
#pragma unroll
        for (int i = 0; i < 4; ++i) wf[i] = *(const bf16x8*)&ldsW[buf][oW + i * 512];
#pragma unroll
        for (int j = 0; j < 4; ++j) xf[j] = *(const bf16x8*)&ldsX[buf][oX + j * 512];
#pragma unroll
        for (int i = 0; i < 4; ++i)
#pragma unroll
            for (int j = 0; j < 4; ++j)
                acc[i][j] = __builtin_amdgcn_mfma_f32_16x16x32_bf16(wf[i], xf[j], acc[i][j], 0, 0, 0);
        asm volatile("s_waitcnt vmcnt(0)" ::: "memory");
        __syncthreads();
    }
#undef STAGE

    // epilogue: head-major scatter, 8B vector stores.
    const bool sideK = (n0 >= 1024);
    unsigned short* dst = sideK ? KH : QH;

    int rowoff[4];   // per xrow fragment j (row = lane&15 of D)
#pragma unroll
    for (int j = 0; j < 4; ++j) {
        const int g = m0 + xc + 16 * j + lr;
        const int b = g >> 12, rr = g & 4095;
        int v = -1;
        if (rr >= 2049) {
            const int seg = b * 2 + (sideK ? 0 : 1);
            v = seg * (NH_ * 2048 * 32) + (rr - 2049) * 32;
        } else if (rr >= 1) {
            const int seg = b * 2 + (sideK ? 1 : 0);
            v = seg * (NH_ * 2048 * 32) + (rr - 1) * 32;
        }
        rowoff[j] = v;
    }

    int coloff[4]; f32x4 bias4[4];   // per channel fragment i (4 consec chans)
#pragma unroll
    for (int i = 0; i < 4; ++i) {
        const int c = n0 + cr + 16 * i + lg * 4;
        const int local = c - (sideK ? 1024 : 0);
        coloff[i] = (local >> 5) * (2048 * 32) + (local & 31);
        bias4[i] = *(const f32x4*)&bb[c];
    }

#pragma unroll
    for (int j = 0; j < 4; ++j) {
        if (rowoff[j] < 0) continue;
#pragma unroll
        for (int i = 0; i < 4; ++i) {
            u16x4 o;
#pragma unroll
            for (int r = 0; r < 4; ++r) o[r] = f2bf(acc[i][j][r] + bias4[i][r]);
            *(u16x4*)&dst[(size_t)rowoff[j] + coloff[i]] = o;
        }
    }
}

// ---------------------------------------------------------------------------
// Pass 1: negL[bm][q] = -log2( sum_k exp2(s2[q][k]) ), s2 = log2-domain score.
// grid (8, 32 heads, 6 bm); each wave owns 64 q rows (4 A-frags), streams K.
// (round-5 body: simple loop, no explicit prefetch — compiler schedules fine)
// ---------------------------------------------------------------------------
__global__ __launch_bounds__(256) void zpass(const unsigned short* __restrict__ QH,
                                             const unsigned short* __restrict__ KH,
                                             float* __restrict__ NL)
{
    const int tid = threadIdx.x, lane = tid & 63, w = tid >> 6;
    const int bm = blockIdx.z, mha = bm & 1;
    const int h = blockIdx.y;
    const int nq = mha ? NQ2 : NQ1, nk = mha ? NK2 : NK1;
    const size_t panel = ((size_t)bm * NH_ + h) * 2048 * 32;
    const int lr = lane & 15, lg = lane >> 4;
    const int q0 = blockIdx.x * 256 + w * 64;
    const f32x4 zero = {0.f, 0.f, 0.f, 0.f};

    const unsigned short* Qp = QH + panel + (size_t)(q0 + lr) * 32 + lg * 8;
    const unsigned short* Kp = KH + panel + (size_t)lr * 32 + lg * 8;

    bf16x8 a[4];
#pragma unroll
    for (int i = 0; i < 4; ++i) a[i] = *(const bf16x8*)(Qp + i * 16 * 32);

    float z[4][4] = {};
    for (int kt = 0; kt < 127; ++kt) {
        const bf16x8 kb = *(const bf16x8*)(Kp + (size_t)kt * 16 * 32);
#pragma unroll
        for (int i = 0; i < 4; ++i) {
            const f32x4 d = __builtin_amdgcn_mfma_f32_16x16x32_bf16(a[i], kb, zero, 0, 0, 0);
#pragma unroll
            for (int r = 0; r < 4; ++r) z[i][r] += EXP2(d[r]);
        }
    }
    {   // tail k-tile with column mask (masks pad col 2047 for mha0)
        const bf16x8 kb = *(const bf16x8*)(Kp + (size_t)127 * 16 * 32);
        const float m = (2032 + lr < nk) ? 1.f : 0.f;
#pragma unroll
        for (int i = 0; i < 4; ++i) {
            const f32x4 d = __builtin_amdgcn_mfma_f32_16x16x32_bf16(a[i], kb, zero, 0, 0, 0);
#pragma unroll
            for (int r = 0; r < 4; ++r) z[i][r] += m * EXP2(d[r]);
        }
    }

#pragma unroll
    for (int i = 0; i < 4; ++i) {
#pragma unroll
        for (int r = 0; r < 4; ++r) {
            float v = z[i][r];
            v += __shfl_xor(v, 1, 64);
            v += __shfl_xor(v, 2, 64);
            v += __shfl_xor(v, 4, 64);
            v += __shfl_xor(v, 8, 64);
            z[i][r] = v;
        }
        if (lr == 0) {
            const int qb = q0 + i * 16 + lg * 4;
            f32x4 o;
#pragma unroll
            for (int r = 0; r < 4; ++r)
                o[r] = (qb + r < nq) ? -LOG2(z[i][r]) : -1e30f;  // -inf masks pad q
            *(f32x4*)&NL[(size_t)bm * 2048 + qb] = o;
        }
    }
}

// ---------------------------------------------------------------------------
// Pass 2: CS[bm][h][k] = sum_q exp2(s2[q][k] + negL[q]).  negL rides in the
// MFMA accumulator (per-output-row constant), so per score = exp2 + add.
// (round-5 body)
// ---------------------------------------------------------------------------
__global__ __launch_bounds__(256) void colsum(const unsigned short* __restrict__ QH,
                                              const unsigned short* __restrict__ KH,
                                              const float* __restrict__ NL,
                                              float* __restrict__ CS)
{
    const int tid = threadIdx.x, lane = tid & 63, w = tid >> 6;
    const int bm = blockIdx.z, mha = bm & 1;
    const int h = blockIdx.y;
    const int nk = mha ? NK2 : NK1;
    const size_t panel = ((size_t)bm * NH_ + h) * 2048 * 32;
    const int lr = lane & 15, lg = lane >> 4;
    const int kc = blockIdx.x * 256 + w * 64;

    const unsigned short* Kp = KH + panel + (size_t)(kc + lr) * 32 + lg * 8;
    const unsigned short* Qp = QH + panel + (size_t)lr * 32 + lg * 8;
    const float* zp = NL + (size_t)bm * 2048 + lg * 4;

    bf16x8 kb[4];
#pragma unroll
    for (int j = 0; j < 4; ++j) kb[j] = *(const bf16x8*)(Kp + j * 16 * 32);

    float cacc[4] = {};
    for (int qt = 0; qt < 128; ++qt) {
        const bf16x8 ai = *(const bf16x8*)(Qp + (size_t)qt * 16 * 32);
        const f32x4 cv = *(const f32x4*)(zp + qt * 16);
#pragma unroll
        for (int j = 0; j < 4; ++j) {
            const f32x4 d = __builtin_amdgcn_mfma_f32_16x16x32_bf16(ai, kb[j], cv, 0, 0, 0);
#pragma unroll
            for (int r = 0; r < 4; ++r) cacc[j] += EXP2(d[r]);
        }
    }

#pragma unroll
    for (int j = 0; j < 4; ++j) {
        float v = cacc[j];
        v += __shfl_xor(v, 16, 64);
        v += __shfl_xor(v, 32, 64);
        const int col = kc + 16 * j + lr;
        if (lane < 16 && col < nk)
            CS[((size_t)bm * NH_ + h) * 2048 + col] = v;
    }
}

// ---------------------------------------------------------------------------
// Pass C: u[bm][h][c] = sum_k CS[bm][h][k] * Xb[kbase+k][c]   (bf16 X)
// grid (32 ktiles of 64, 4 headgroups, 6 bm)
// ---------------------------------------------------------------------------
__global__ __launch_bounds__(256) void colsum_x(
    const unsigned short* __restrict__ Xb, const float* __restrict__ CS,
    float* __restrict__ U)
{
    __shared__ float sl[8][64];
    const int tid = threadIdx.x;
    const int bm = blockIdx.z;
    const int b = bm >> 1, mha = bm & 1;
    const int kbase = mha ? SEG1 : SEG2;
    const int nk = mha ? NK2 : NK1;
    const int kt = blockIdx.x * 64;
    const int hg = blockIdx.y * 8;

    for (int idx = tid; idx < 8 * 64; idx += 256) {
        const int hh = idx >> 6, kk = idx & 63;
        const int k = kt + kk;
        sl[hh][kk] = (k < nk) ? CS[((size_t)bm * NH_ + hg + hh) * 2048 + k] : 0.f;
    }
    __syncthreads();

    float acc[8][4] = {};
    const int c4 = tid * 4;
    for (int kk = 0; kk < 64; ++kk) {
        const int k = kt + kk;
        if (k >= nk) break;   // uniform across block
        const u16x4 xv = *(const u16x4*)&Xb[((size_t)b * S_ + kbase + k) * H_ + c4];
        const float x0 = bf2f(xv[0]), x1 = bf2f(xv[1]), x2 = bf2f(xv[2]), x3 = bf2f(xv[3]);
#pragma unroll
        for (int hh = 0; hh < 8; ++hh) {
            const float sv = sl[hh][kk];
            acc[hh][0] += sv * x0; acc[hh][1] += sv * x1;
            acc[hh][2] += sv * x2; acc[hh][3] += sv * x3;
        }
    }
#pragma unroll
    for (int hh = 0; hh < 8; ++hh)
#pragma unroll
        for (int c = 0; c < 4; ++c)
            atomicAdd(&U[((size_t)bm * NH_ + hg + hh) * H_ + c4 + c], acc[hh][c]);
}

// ---------------------------------------------------------------------------
__global__ __launch_bounds__(256) void compute_m(
    const float* __restrict__ U, const float* __restrict__ Wv,
    const float* __restrict__ bv, float* __restrict__ Mvec)
{
    const int bm = blockIdx.y;
    const int mha = bm & 1;
    const float invnq = 1.f / (float)(mha ? NQ2 : NQ1);
    const int o = blockIdx.x * 256 + threadIdx.x;
    const int hh = o >> 5;
    const float* u = &U[((size_t)bm * NH_ + hh) * H_];
    const float* w = &Wv[(size_t)o * H_];
    float acc = 0.f;
    for (int in = 0; in < H_; in += 4) {
        const float4 uv = *(const float4*)&u[in];
        const float4 wv = *(const float4*)&w[in];
        acc += uv.x * wv.x + uv.y * wv.y + uv.z * wv.z + uv.w * wv.w;
    }
    Mvec[(size_t)bm * H_ + o] = acc * invnq + bv[o];
}

__global__ __launch_bounds__(256) void final_out(
    const float* __restrict__ Mvec, const float* __restrict__ Wo,
    const float* __restrict__ bo, float* __restrict__ out)
{
    const int bm = blockIdx.y;
    const int b = bm >> 1, mha = bm & 1;
    const int o = blockIdx.x * 256 + threadIdx.x;
    const float* mv = &Mvec[(size_t)bm * H_];
    const float* w = &Wo[(size_t)o * H_];
    float acc = 0.f;
    for (int in = 0; in < H_; in += 4) {
        const float4 mvv = *(const float4*)&mv[in];
        const float4 wv = *(const float4*)&w[in];
        acc += mvv.x * wv.x + mvv.y * wv.y + mvv.z * wv.z + mvv.w * wv.w;
    }
    out[(size_t)b * 2048 + mha * 1024 + o] = acc + bo[o];
}

// ---------------------------------------------------------------------------
extern "C" void kernel_launch(void* const* d_in, const int* in_sizes, int n_in,
                              void* d_out, int out_size, void* d_ws, size_t ws_size,
                              hipStream_t stream)
{
    const float* hidden = (const float*)d_in[0];
    const float* Wq = (const float*)d_in[7];
    const float* bq = (const float*)d_in[8];
    const float* Wk = (const float*)d_in[9];
    const float* bk = (const float*)d_in[10];
    const float* Wv = (const float*)d_in[11];
    const float* bv = (const float*)d_in[12];
    const float* Wo = (const float*)d_in[13];
    const float* bo = (const float*)d_in[14];
    float* out = (float*)d_out;
    char* ws = (char*)d_ws;

    unsigned short* Xb  = (unsigned short*)(ws + oXb);
    unsigned short* Wb  = (unsigned short*)(ws + oWb);
    float* bb           = (float*)(ws + oBB);
    unsigned short* QHp = (unsigned short*)(ws + oQH);
    unsigned short* KHp = (unsigned short*)(ws + oKH);
    float* NL           = (float*)(ws + oNL);
    float* CS           = (float*)(ws + oCS);
    float* U            = (float*)(ws + oU);
    float* Mv           = (float*)(ws + oMv);

    hipMemsetAsync(U, 0, (size_t)6 * NH_ * H_ * sizeof(float), stream);

    const dim3 blk(256);
    conv_x<<<12288, blk, 0, stream>>>(hidden, Xb);
    conv_w<<<2048, blk, 0, stream>>>(Wq, bq, Wk, bk, Wb, bb, QHp, KHp);
    proj_mfma<<<dim3(96, 16), blk, 0, stream>>>(Xb, Wb, bb, QHp, KHp);
    zpass<<<dim3(8, 32, 6), blk, 0, stream>>>(QHp, KHp, NL);
    colsum<<<dim3(8, 32, 6), blk, 0, stream>>>(QHp, KHp, NL, CS);
    colsum_x<<<dim3(32, 4, 6), blk, 0, stream>>>(Xb, CS, U);
    compute_m<<<dim3(4, 6), blk, 0, stream>>>(U, Wv, bv, Mv);
    final_out<<<dim3(4, 6), blk, 0, stream>>>(Mv, Wo, bo, out);
}

// Round 8
// 418.624 us; speedup vs baseline: 3.3295x; 1.2226x over previous
//
#include <hip/hip_runtime.h>
#include <cstddef>

typedef __attribute__((ext_vector_type(8))) short bf16x8;
typedef __attribute__((ext_vector_type(4))) float f32x4;
typedef __attribute__((ext_vector_type(4))) unsigned short u16x4;
typedef __attribute__((ext_vector_type(8))) unsigned short u16x8;

namespace {
constexpr int B_ = 3, S_ = 4096, H_ = 1024, NH_ = 32;
constexpr int SEG1 = 1, SEG2 = 2049;
constexpr int NQ1 = 2048, NK1 = 2047, NQ2 = 2047, NK2 = 2048;
constexpr float SCALE = 0.17677669529663687f;              // 1/sqrt(32)
constexpr float LOG2E = 1.4426950408889634f;
constexpr float QSC   = SCALE * LOG2E;                     // folded into Wq/bq

// workspace byte offsets (all 16B aligned)
constexpr size_t oXb = 0;                                   // 12288*1024 bf16
constexpr size_t oWb = oXb + (size_t)12288 * 1024 * 2;      // 2048*1024 bf16
constexpr size_t oBB = oWb + (size_t)2048 * 1024 * 2;       // 2048 f32
constexpr size_t oQH = oBB + (size_t)2048 * 4;              // 6*32*2048*32 bf16
constexpr size_t oKH = oQH + (size_t)6 * 32 * 2048 * 32 * 2;
constexpr size_t oNL = oKH + (size_t)6 * 32 * 2048 * 32 * 2;  // negL 6*2048 f32
constexpr size_t oCS = oNL + (size_t)6 * 2048 * 4;          // 6*32*2048 f32
constexpr size_t oU  = oCS + (size_t)6 * 32 * 2048 * 4;     // 6*32*1024 f32
constexpr size_t oMv = oU  + (size_t)6 * 32 * 1024 * 4;     // 6*1024 f32
constexpr size_t oUP = oMv + (size_t)6 * 1024 * 4;          // 192*16*1024 f32 partials
}

#if __has_builtin(__builtin_amdgcn_exp2f)
#define EXP2(x) __builtin_amdgcn_exp2f(x)
#else
#define EXP2(x) exp2f(x)
#endif
#if __has_builtin(__builtin_amdgcn_logf)
#define LOG2(x) __builtin_amdgcn_logf(x)
#else
#define LOG2(x) log2f(x)
#endif

__device__ __forceinline__ unsigned short f2bf(float f) {
    unsigned u = __float_as_uint(f);
    u += 0x7FFF + ((u >> 16) & 1);   // RTNE
    return (unsigned short)(u >> 16);
}
__device__ __forceinline__ float bf2f(unsigned short u) {
    return __uint_as_float((unsigned)u << 16);
}
__device__ __forceinline__ void gl16(const unsigned short* gp, unsigned short* lp) {
    __builtin_amdgcn_global_load_lds(
        (const __attribute__((address_space(1))) unsigned int*)gp,
        (__attribute__((address_space(3))) unsigned int*)lp, 16, 0, 0);
}

// ---------------------------------------------------------------------------
__global__ __launch_bounds__(256) void conv_x(const float* __restrict__ X,
                                              unsigned short* __restrict__ Xb)
{
    const size_t i4 = (size_t)blockIdx.x * 256 + threadIdx.x;
    const float4 v = *(const float4*)&X[i4 * 4];
    u16x4 o;
    o[0] = f2bf(v.x); o[1] = f2bf(v.y); o[2] = f2bf(v.z); o[3] = f2bf(v.w);
    *(u16x4*)&Xb[i4 * 4] = o;
}

// pack [QSC*Wq ; Wk] -> bf16, [QSC*bq ; bk] -> f32; also zero pad rows of QH/KH
__global__ __launch_bounds__(256) void conv_w(const float* __restrict__ Wq,
                                              const float* __restrict__ bq,
                                              const float* __restrict__ Wk,
                                              const float* __restrict__ bk,
                                              unsigned short* __restrict__ Wb,
                                              float* __restrict__ bb,
                                              unsigned short* __restrict__ QH,
                                              unsigned short* __restrict__ KH)
{
    const int i4 = blockIdx.x * 256 + threadIdx.x;
    const int base = i4 * 4;
    const bool isQ = base < (1 << 20);
    const float sc = isQ ? QSC : 1.f;
    const float* src = isQ ? &Wq[base] : &Wk[base - (1 << 20)];
    const float4 v = *(const float4*)src;
    u16x4 o;
    o[0] = f2bf(v.x * sc); o[1] = f2bf(v.y * sc);
    o[2] = f2bf(v.z * sc); o[3] = f2bf(v.w * sc);
    *(u16x4*)&Wb[base] = o;
    if (base < 2048) {
#pragma unroll
        for (int c = 0; c < 4; ++c) {
            const int j = base + c;
            bb[j] = (j < 1024) ? QSC * bq[j] : bk[j - 1024];
        }
    }
    if (i4 < 3072) {   // zero pad rows (idx 2047 of mha1-Q and mha0-K panels)
        const int b = i4 >> 10, rem = i4 & 1023, h = rem >> 5, c = rem & 31;
        QH[(((size_t)(b * 2 + 1) * NH_ + h) * 2048 + 2047) * 32 + c] = 0;
        KH[(((size_t)(b * 2 + 0) * NH_ + h) * 2048 + 2047) * 32 + c] = 0;
    }
}

// ---------------------------------------------------------------------------
// Fused Q|K projection -> head-major scatter.  A-operand = W (channels on the
// D row dim), B-operand = X (rows on the D col dim) so each lane owns 4
// CONSECUTIVE dk channels -> vectorized 8B scatter stores.
// ---------------------------------------------------------------------------
__global__ __launch_bounds__(256) void proj_mfma(const unsigned short* __restrict__ Xb,
                                                 const unsigned short* __restrict__ Wb,
                                                 const float* __restrict__ bb,
                                                 unsigned short* __restrict__ QH,
                                                 unsigned short* __restrict__ KH)
{
    __shared__ unsigned short ldsX[2][4096];   // [buf][128 rows * 32 (=BK)]
    __shared__ unsigned short ldsW[2][4096];
    const int tid = threadIdx.x;
    const int lane = tid & 63, w = tid >> 6;
    const int m0 = blockIdx.x * 128;   // x-rows
    const int n0 = blockIdx.y * 128;   // output channels (Q: 0..1023, K: 1024..2047)
    const int cr = (w >> 1) * 64;      // channel half owned by this wave
    const int xc = (w & 1) * 64;       // xrow half owned by this wave

    // staging: lane -> row (lane>>2), granule pre-swizzled g ^ ((row>>1)&3)
    const int co = ((lane & 3) ^ ((lane >> 3) & 3)) * 8;
    const unsigned short* gX = Xb + (size_t)(m0 + 32 * w + (lane >> 2)) * 1024 + co;
    const unsigned short* gW = Wb + (size_t)(n0 + 32 * w + (lane >> 2)) * 1024 + co;

#define STAGE(K0, BUF) do { \
    gl16(gX + (K0),             &ldsX[BUF][(32 * w) * 32]); \
    gl16(gX + (K0) + 16 * 1024, &ldsX[BUF][(32 * w + 16) * 32]); \
    gl16(gW + (K0),             &ldsW[BUF][(32 * w) * 32]); \
    gl16(gW + (K0) + 16 * 1024, &ldsW[BUF][(32 * w + 16) * 32]); \
} while (0)

    // fragment read offsets (same XOR on the read side; row+16 keeps same XOR)
    const int lr = lane & 15, lg = lane >> 4;
    const int mrW = cr + lr, mrX = xc + lr;
    const int oW = mrW * 32 + ((lg ^ ((mrW >> 1) & 3)) * 8);
    const int oX = mrX * 32 + ((lg ^ ((mrX >> 1) & 3)) * 8);

    f32x4 acc[4][4] = {};
    STAGE(0, 0);
    asm volatile("s_waitcnt vmcnt(0)" ::: "memory");
    __syncthreads();

    for (int kt = 0; kt < 32; ++kt) {
        const int buf = kt & 1;
        if (kt < 31) STAGE((kt + 1) * 32, buf ^ 1);
        bf16x8 wf[4], xf[4];
#pragma unroll
        for (int i = 0; i < 4; ++i) wf[i] = *(const bf16x8*)&ldsW[buf][oW + i * 512];
#pragma unroll
        for (int j = 0; j < 4; ++j) xf[j] = *(const bf16x8*)&ldsX[buf][oX + j * 512];
#pragma unroll
        for (int i = 0; i < 4; ++i)
#pragma unroll
            for (int j = 0; j < 4; ++j)
                acc[i][j] = __builtin_amdgcn_mfma_f32_16x16x32_bf16(wf[i], xf[j], acc[i][j], 0, 0, 0);
        asm volatile("s_waitcnt vmcnt(0)" ::: "memory");
        __syncthreads();
    }
#undef STAGE

    // epilogue: head-major scatter, 8B vector stores.
    const bool sideK = (n0 >= 1024);
    unsigned short* dst = sideK ? KH : QH;

    int rowoff[4];   // per xrow fragment j (row = lane&15 of D)
#pragma unroll
    for (int j = 0; j < 4; ++j) {
        const int g = m0 + xc + 16 * j + lr;
        const int b = g >> 12, rr = g & 4095;
        int v = -1;
        if (rr >= 2049) {
            const int seg = b * 2 + (sideK ? 0 : 1);
            v = seg * (NH_ * 2048 * 32) + (rr - 2049) * 32;
        } else if (rr >= 1) {
            const int seg = b * 2 + (sideK ? 1 : 0);
            v = seg * (NH_ * 2048 * 32) + (rr - 1) * 32;
        }
        rowoff[j] = v;
    }

    int coloff[4]; f32x4 bias4[4];   // per channel fragment i (4 consec chans)
#pragma unroll
    for (int i = 0; i < 4; ++i) {
        const int c = n0 + cr + 16 * i + lg * 4;
        const int local = c - (sideK ? 1024 : 0);
        coloff[i] = (local >> 5) * (2048 * 32) + (local & 31);
        bias4[i] = *(const f32x4*)&bb[c];
    }

#pragma unroll
    for (int j = 0; j < 4; ++j) {
        if (rowoff[j] < 0) continue;
#pragma unroll
        for (int i = 0; i < 4; ++i) {
            u16x4 o;
#pragma unroll
            for (int r = 0; r < 4; ++r) o[r] = f2bf(acc[i][j][r] + bias4[i][r]);
            *(u16x4*)&dst[(size_t)rowoff[j] + coloff[i]] = o;
        }
    }
}

// ---------------------------------------------------------------------------
// Pass 1: negL[bm][q] = -log2( sum_k exp2(s2[q][k]) ), s2 = log2-domain score.
// grid (8, 32 heads, 6 bm); each wave owns 64 q rows (4 A-frags), streams K.
// Vector (f32x4) accumulators -> packed adds.
// ---------------------------------------------------------------------------
__global__ __launch_bounds__(256) void zpass(const unsigned short* __restrict__ QH,
                                             const unsigned short* __restrict__ KH,
                                             float* __restrict__ NL)
{
    const int tid = threadIdx.x, lane = tid & 63, w = tid >> 6;
    const int bm = blockIdx.z, mha = bm & 1;
    const int h = blockIdx.y;
    const int nq = mha ? NQ2 : NQ1, nk = mha ? NK2 : NK1;
    const size_t panel = ((size_t)bm * NH_ + h) * 2048 * 32;
    const int lr = lane & 15, lg = lane >> 4;
    const int q0 = blockIdx.x * 256 + w * 64;
    const f32x4 zero = {0.f, 0.f, 0.f, 0.f};

    const unsigned short* Qp = QH + panel + (size_t)(q0 + lr) * 32 + lg * 8;
    const unsigned short* Kp = KH + panel + (size_t)lr * 32 + lg * 8;

    bf16x8 a[4];
#pragma unroll
    for (int i = 0; i < 4; ++i) a[i] = *(const bf16x8*)(Qp + i * 16 * 32);

    f32x4 z[4] = {zero, zero, zero, zero};
    for (int kt = 0; kt < 127; ++kt) {
        const bf16x8 kb = *(const bf16x8*)(Kp + (size_t)kt * 16 * 32);
#pragma unroll
        for (int i = 0; i < 4; ++i) {
            const f32x4 d = __builtin_amdgcn_mfma_f32_16x16x32_bf16(a[i], kb, zero, 0, 0, 0);
            f32x4 e;
#pragma unroll
            for (int r = 0; r < 4; ++r) e[r] = EXP2(d[r]);
            z[i] += e;
        }
    }
    {   // tail k-tile with column mask (masks pad col 2047 for mha0)
        const bf16x8 kb = *(const bf16x8*)(Kp + (size_t)127 * 16 * 32);
        const float m = (2032 + lr < nk) ? 1.f : 0.f;
#pragma unroll
        for (int i = 0; i < 4; ++i) {
            const f32x4 d = __builtin_amdgcn_mfma_f32_16x16x32_bf16(a[i], kb, zero, 0, 0, 0);
            f32x4 e;
#pragma unroll
            for (int r = 0; r < 4; ++r) e[r] = m * EXP2(d[r]);
            z[i] += e;
        }
    }

#pragma unroll
    for (int i = 0; i < 4; ++i) {
        f32x4 zi = z[i];
#pragma unroll
        for (int r = 0; r < 4; ++r) {
            float v = zi[r];
            v += __shfl_xor(v, 1, 64);
            v += __shfl_xor(v, 2, 64);
            v += __shfl_xor(v, 4, 64);
            v += __shfl_xor(v, 8, 64);
            zi[r] = v;
        }
        if (lr == 0) {
            const int qb = q0 + i * 16 + lg * 4;
            f32x4 o;
#pragma unroll
            for (int r = 0; r < 4; ++r)
                o[r] = (qb + r < nq) ? -LOG2(zi[r]) : -1e30f;  // -inf masks pad q
            *(f32x4*)&NL[(size_t)bm * 2048 + qb] = o;
        }
    }
}

// ---------------------------------------------------------------------------
// Pass 2: CS[bm][h][k] = sum_q exp2(s2[q][k] + negL[q]).  negL rides in the
// MFMA accumulator; vector accumulators.
// ---------------------------------------------------------------------------
__global__ __launch_bounds__(256) void colsum(const unsigned short* __restrict__ QH,
                                              const unsigned short* __restrict__ KH,
                                              const float* __restrict__ NL,
                                              float* __restrict__ CS)
{
    const int tid = threadIdx.x, lane = tid & 63, w = tid >> 6;
    const int bm = blockIdx.z, mha = bm & 1;
    const int h = blockIdx.y;
    const int nk = mha ? NK2 : NK1;
    const size_t panel = ((size_t)bm * NH_ + h) * 2048 * 32;
    const int lr = lane & 15, lg = lane >> 4;
    const int kc = blockIdx.x * 256 + w * 64;
    const f32x4 zero = {0.f, 0.f, 0.f, 0.f};

    const unsigned short* Kp = KH + panel + (size_t)(kc + lr) * 32 + lg * 8;
    const unsigned short* Qp = QH + panel + (size_t)lr * 32 + lg * 8;
    const float* zp = NL + (size_t)bm * 2048 + lg * 4;

    bf16x8 kb[4];
#pragma unroll
    for (int j = 0; j < 4; ++j) kb[j] = *(const bf16x8*)(Kp + j * 16 * 32);

    f32x4 cacc[4] = {zero, zero, zero, zero};
    for (int qt = 0; qt < 128; ++qt) {
        const bf16x8 ai = *(const bf16x8*)(Qp + (size_t)qt * 16 * 32);
        const f32x4 cv = *(const f32x4*)(zp + qt * 16);
#pragma unroll
        for (int j = 0; j < 4; ++j) {
            const f32x4 d = __builtin_amdgcn_mfma_f32_16x16x32_bf16(ai, kb[j], cv, 0, 0, 0);
            f32x4 e;
#pragma unroll
            for (int r = 0; r < 4; ++r) e[r] = EXP2(d[r]);
            cacc[j] += e;
        }
    }

#pragma unroll
    for (int j = 0; j < 4; ++j) {
        float v = (cacc[j][0] + cacc[j][1]) + (cacc[j][2] + cacc[j][3]);
        v += __shfl_xor(v, 16, 64);
        v += __shfl_xor(v, 32, 64);
        const int col = kc + 16 * j + lr;
        if (lane < 16 && col < nk)
            CS[((size_t)bm * NH_ + h) * 2048 + col] = v;
    }
}

// ---------------------------------------------------------------------------
// Pass C stage 1: UP[bm*32+h][kt][c] = sum_{k in tile} CS[bm][h][k]*Xb[k][c]
// grid (kt=16, hg=4, bm=6); NO atomics — pure coalesced stores.
// ---------------------------------------------------------------------------
__global__ __launch_bounds__(256) void colsum_x(
    const unsigned short* __restrict__ Xb, const float* __restrict__ CS,
    float* __restrict__ UP)
{
    __shared__ float sl[8][128];
    const int tid = threadIdx.x;
    const int bm = blockIdx.z;
    const int b = bm >> 1, mha = bm & 1;
    const int kbase = mha ? SEG1 : SEG2;
    const int nk = mha ? NK2 : NK1;
    const int kt = blockIdx.x;           // 0..15, k-tile of 128
    const int k0 = kt * 128;
    const int hg = blockIdx.y * 8;

    for (int idx = tid; idx < 8 * 128; idx += 256) {
        const int hh = idx >> 7, kk = idx & 127;
        const int k = k0 + kk;
        sl[hh][kk] = (k < nk) ? CS[((size_t)bm * NH_ + hg + hh) * 2048 + k] : 0.f;
    }
    __syncthreads();

    float acc[8][4] = {};
    const int c4 = tid * 4;
#pragma unroll 4
    for (int kk = 0; kk < 128; ++kk) {
        const int k = k0 + kk;
        const int krow = (k < nk) ? k : 0;    // sl==0 masks the product
        const u16x4 xv = *(const u16x4*)&Xb[((size_t)b * S_ + kbase + krow) * H_ + c4];
        const float x0 = bf2f(xv[0]), x1 = bf2f(xv[1]), x2 = bf2f(xv[2]), x3 = bf2f(xv[3]);
#pragma unroll
        for (int hh = 0; hh < 8; ++hh) {
            const float sv = sl[hh][kk];
            acc[hh][0] += sv * x0; acc[hh][1] += sv * x1;
            acc[hh][2] += sv * x2; acc[hh][3] += sv * x3;
        }
    }
#pragma unroll
    for (int hh = 0; hh < 8; ++hh) {
        f32x4 o; o[0] = acc[hh][0]; o[1] = acc[hh][1]; o[2] = acc[hh][2]; o[3] = acc[hh][3];
        *(f32x4*)&UP[((size_t)(bm * NH_ + hg + hh) * 16 + kt) * 1024 + c4] = o;
    }
}

// Pass C stage 2: U[row][c] = sum_kt UP[row][kt][c]
__global__ __launch_bounds__(256) void reduce_u(const float* __restrict__ UP,
                                                float* __restrict__ U)
{
    const int gid = blockIdx.x * 256 + threadIdx.x;   // 0..49151
    const int row = gid >> 8;                          // bm*32+h
    const int c4 = (gid & 255) * 4;
    const float* p = UP + (size_t)row * 16 * 1024 + c4;
    f32x4 s = *(const f32x4*)p;
#pragma unroll
    for (int t = 1; t < 16; ++t) s += *(const f32x4*)(p + t * 1024);
    *(f32x4*)&U[(size_t)row * 1024 + c4] = s;
}

// ---------------------------------------------------------------------------
__global__ __launch_bounds__(256) void compute_m(
    const float* __restrict__ U, const float* __restrict__ Wv,
    const float* __restrict__ bv, float* __restrict__ Mvec)
{
    const int bm = blockIdx.y;
    const int mha = bm & 1;
    const float invnq = 1.f / (float)(mha ? NQ2 : NQ1);
    const int o = blockIdx.x * 256 + threadIdx.x;
    const int hh = o >> 5;
    const float* u = &U[((size_t)bm * NH_ + hh) * H_];
    const float* w = &Wv[(size_t)o * H_];
    float acc = 0.f;
    for (int in = 0; in < H_; in += 4) {
        const float4 uv = *(const float4*)&u[in];
        const float4 wv = *(const float4*)&w[in];
        acc += uv.x * wv.x + uv.y * wv.y + uv.z * wv.z + uv.w * wv.w;
    }
    Mvec[(size_t)bm * H_ + o] = acc * invnq + bv[o];
}

__global__ __launch_bounds__(256) void final_out(
    const float* __restrict__ Mvec, const float* __restrict__ Wo,
    const float* __restrict__ bo, float* __restrict__ out)
{
    const int bm = blockIdx.y;
    const int b = bm >> 1, mha = bm & 1;
    const int o = blockIdx.x * 256 + threadIdx.x;
    const float* mv = &Mvec[(size_t)bm * H_];
    const float* w = &Wo[(size_t)o * H_];
    float acc = 0.f;
    for (int in = 0; in < H_; in += 4) {
        const float4 mvv = *(const float4*)&mv[in];
        const float4 wv = *(const float4*)&w[in];
        acc += mvv.x * wv.x + mvv.y * wv.y + mvv.z * wv.z + mvv.w * wv.w;
    }
    out[(size_t)b * 2048 + mha * 1024 + o] = acc + bo[o];
}

// ---------------------------------------------------------------------------
extern "C" void kernel_launch(void* const* d_in, const int* in_sizes, int n_in,
                              void* d_out, int out_size, void* d_ws, size_t ws_size,
                              hipStream_t stream)
{
    const float* hidden = (const float*)d_in[0];
    const float* Wq = (const float*)d_in[7];
    const float* bq = (const float*)d_in[8];
    const float* Wk = (const float*)d_in[9];
    const float* bk = (const float*)d_in[10];
    const float* Wv = (const float*)d_in[11];
    const float* bv = (const float*)d_in[12];
    const float* Wo = (const float*)d_in[13];
    const float* bo = (const float*)d_in[14];
    float* out = (float*)d_out;
    char* ws = (char*)d_ws;

    unsigned short* Xb  = (unsigned short*)(ws + oXb);
    unsigned short* Wb  = (unsigned short*)(ws + oWb);
    float* bb           = (float*)(ws + oBB);
    unsigned short* QHp = (unsigned short*)(ws + oQH);
    unsigned short* KHp = (unsigned short*)(ws + oKH);
    float* NL           = (float*)(ws + oNL);
    float* CS           = (float*)(ws + oCS);
    float* U            = (float*)(ws + oU);
    float* Mv           = (float*)(ws + oMv);
    float* UP           = (float*)(ws + oUP);

    const dim3 blk(256);
    conv_x<<<12288, blk, 0, stream>>>(hidden, Xb);
    conv_w<<<2048, blk, 0, stream>>>(Wq, bq, Wk, bk, Wb, bb, QHp, KHp);
    proj_mfma<<<dim3(96, 16), blk, 0, stream>>>(Xb, Wb, bb, QHp, KHp);
    zpass<<<dim3(8, 32, 6), blk, 0, stream>>>(QHp, KHp, NL);
    colsum<<<dim3(8, 32, 6), blk, 0, stream>>>(QHp, KHp, NL, CS);
    colsum_x<<<dim3(16, 4, 6), blk, 0, stream>>>(Xb, CS, UP);
    reduce_u<<<192, blk, 0, stream>>>(UP, U);
    compute_m<<<dim3(4, 6), blk, 0, stream>>>(U, Wv, bv, Mv);
    final_out<<<dim3(4, 6), blk, 0, stream>>>(Mv, Wo, bo, out);
}

// Round 9
// 378.721 us; speedup vs baseline: 3.6803x; 1.1054x over previous
//
#include <hip/hip_runtime.h>
#include <cstddef>

typedef __attribute__((ext_vector_type(8))) short bf16x8;
typedef __attribute__((ext_vector_type(4))) float f32x4;
typedef __attribute__((ext_vector_type(4))) unsigned short u16x4;
typedef __attribute__((ext_vector_type(8))) unsigned short u16x8;

namespace {
constexpr int B_ = 3, S_ = 4096, H_ = 1024, NH_ = 32;
constexpr int SEG1 = 1, SEG2 = 2049;
constexpr int NQ1 = 2048, NK1 = 2047, NQ2 = 2047, NK2 = 2048;
constexpr float SCALE = 0.17677669529663687f;              // 1/sqrt(32)
constexpr float LOG2E = 1.4426950408889634f;
constexpr float QSC   = SCALE * LOG2E;                     // folded into Wq/bq

// workspace byte offsets (all 16B aligned)
constexpr size_t oXb = 0;                                   // 12288*1024 bf16
constexpr size_t oWb = oXb + (size_t)12288 * 1024 * 2;      // 2048*1024 bf16
constexpr size_t oBB = oWb + (size_t)2048 * 1024 * 2;       // 2048 f32
constexpr size_t oQH = oBB + (size_t)2048 * 4;              // 6*32*2048*32 bf16
constexpr size_t oKH = oQH + (size_t)6 * 32 * 2048 * 32 * 2;
constexpr size_t oNL = oKH + (size_t)6 * 32 * 2048 * 32 * 2;  // negL 6*2048 f32
constexpr size_t oCS = oNL + (size_t)6 * 2048 * 4;          // 6*32*2048 f32
constexpr size_t oU  = oCS + (size_t)6 * 32 * 2048 * 4;     // 6*32*1024 f32
constexpr size_t oMv = oU  + (size_t)6 * 32 * 1024 * 4;     // 6*1024 f32
constexpr size_t oUP = oMv + (size_t)6 * 1024 * 4;          // 192*16*1024 f32 partials
}

#if __has_builtin(__builtin_amdgcn_exp2f)
#define EXP2(x) __builtin_amdgcn_exp2f(x)
#else
#define EXP2(x) exp2f(x)
#endif
#if __has_builtin(__builtin_amdgcn_logf)
#define LOG2(x) __builtin_amdgcn_logf(x)
#else
#define LOG2(x) log2f(x)
#endif

__device__ __forceinline__ unsigned short f2bf(float f) {
    unsigned u = __float_as_uint(f);
    u += 0x7FFF + ((u >> 16) & 1);   // RTNE
    return (unsigned short)(u >> 16);
}
__device__ __forceinline__ float bf2f(unsigned short u) {
    return __uint_as_float((unsigned)u << 16);
}
__device__ __forceinline__ void gl16(const unsigned short* gp, unsigned short* lp) {
    __builtin_amdgcn_global_load_lds(
        (const __attribute__((address_space(1))) unsigned int*)gp,
        (__attribute__((address_space(3))) unsigned int*)lp, 16, 0, 0);
}

// ---------------------------------------------------------------------------
__global__ __launch_bounds__(256) void conv_x(const float* __restrict__ X,
                                              unsigned short* __restrict__ Xb)
{
    const size_t i4 = (size_t)blockIdx.x * 256 + threadIdx.x;
    const float4 v = *(const float4*)&X[i4 * 4];
    u16x4 o;
    o[0] = f2bf(v.x); o[1] = f2bf(v.y); o[2] = f2bf(v.z); o[3] = f2bf(v.w);
    *(u16x4*)&Xb[i4 * 4] = o;
}

// pack [QSC*Wq ; Wk] -> bf16, [QSC*bq ; bk] -> f32; also zero pad rows of QH/KH
__global__ __launch_bounds__(256) void conv_w(const float* __restrict__ Wq,
                                              const float* __restrict__ bq,
                                              const float* __restrict__ Wk,
                                              const float* __restrict__ bk,
                                              unsigned short* __restrict__ Wb,
                                              float* __restrict__ bb,
                                              unsigned short* __restrict__ QH,
                                              unsigned short* __restrict__ KH)
{
    const int i4 = blockIdx.x * 256 + threadIdx.x;
    const int base = i4 * 4;
    const bool isQ = base < (1 << 20);
    const float sc = isQ ? QSC : 1.f;
    const float* src = isQ ? &Wq[base] : &Wk[base - (1 << 20)];
    const float4 v = *(const float4*)src;
    u16x4 o;
    o[0] = f2bf(v.x * sc); o[1] = f2bf(v.y * sc);
    o[2] = f2bf(v.z * sc); o[3] = f2bf(v.w * sc);
    *(u16x4*)&Wb[base] = o;
    if (base < 2048) {
#pragma unroll
        for (int c = 0; c < 4; ++c) {
            const int j = base + c;
            bb[j] = (j < 1024) ? QSC * bq[j] : bk[j - 1024];
        }
    }
    if (i4 < 3072) {   // zero pad rows (idx 2047 of mha1-Q and mha0-K panels)
        const int b = i4 >> 10, rem = i4 & 1023, h = rem >> 5, c = rem & 31;
        QH[(((size_t)(b * 2 + 1) * NH_ + h) * 2048 + 2047) * 32 + c] = 0;
        KH[(((size_t)(b * 2 + 0) * NH_ + h) * 2048 + 2047) * 32 + c] = 0;
    }
}

// ---------------------------------------------------------------------------
// Fused Q|K projection -> head-major scatter.  A-operand = W, B-operand = X.
// 3-buffer LDS pipeline, counted vmcnt(4) (STAGE(kt+2) stays in flight across
// the barrier), raw s_barrier + sched_barrier(0).
// ---------------------------------------------------------------------------
__global__ __launch_bounds__(256) void proj_mfma(const unsigned short* __restrict__ Xb,
                                                 const unsigned short* __restrict__ Wb,
                                                 const float* __restrict__ bb,
                                                 unsigned short* __restrict__ QH,
                                                 unsigned short* __restrict__ KH)
{
    __shared__ unsigned short ldsX[3 * 4096];   // [buf][128 rows * 32 (=BK)]
    __shared__ unsigned short ldsW[3 * 4096];
    const int tid = threadIdx.x;
    const int lane = tid & 63, w = tid >> 6;
    const int m0 = blockIdx.x * 128;   // x-rows
    const int n0 = blockIdx.y * 128;   // output channels (Q: 0..1023, K: 1024..2047)
    const int cr = (w >> 1) * 64;      // channel half owned by this wave
    const int xc = (w & 1) * 64;       // xrow half owned by this wave

    // staging: lane -> row (lane>>2), granule pre-swizzled g ^ ((row>>1)&3)
    const int co = ((lane & 3) ^ ((lane >> 3) & 3)) * 8;
    const unsigned short* gX = Xb + (size_t)(m0 + 32 * w + (lane >> 2)) * 1024 + co;
    const unsigned short* gW = Wb + (size_t)(n0 + 32 * w + (lane >> 2)) * 1024 + co;

#define STAGE(K0, BUF) do { \
    gl16(gX + (K0),             &ldsX[(BUF) * 4096 + (32 * w) * 32]); \
    gl16(gX + (K0) + 16 * 1024, &ldsX[(BUF) * 4096 + (32 * w + 16) * 32]); \
    gl16(gW + (K0),             &ldsW[(BUF) * 4096 + (32 * w) * 32]); \
    gl16(gW + (K0) + 16 * 1024, &ldsW[(BUF) * 4096 + (32 * w + 16) * 32]); \
} while (0)

    // fragment read offsets (same XOR on the read side; row+16 keeps same XOR)
    const int lr = lane & 15, lg = lane >> 4;
    const int mrW = cr + lr, mrX = xc + lr;
    const int oW = mrW * 32 + ((lg ^ ((mrW >> 1) & 3)) * 8);
    const int oX = mrX * 32 + ((lg ^ ((mrX >> 1) & 3)) * 8);

    f32x4 acc[4][4] = {};
    STAGE(0, 0);
    STAGE(32, 1);
    asm volatile("s_waitcnt vmcnt(4)" ::: "memory");   // STAGE(0) landed
    __builtin_amdgcn_s_barrier();
    __builtin_amdgcn_sched_barrier(0);

    int cur = 0, stg = 2;
    for (int kt = 0; kt < 32; ++kt) {
        const int cb = cur * 4096;
        bf16x8 wf[4], xf[4];
#pragma unroll
        for (int i = 0; i < 4; ++i) wf[i] = *(const bf16x8*)&ldsW[cb + oW + i * 512];
#pragma unroll
        for (int j = 0; j < 4; ++j) xf[j] = *(const bf16x8*)&ldsX[cb + oX + j * 512];
        if (kt + 2 < 32) STAGE((kt + 2) * 32, stg);
#pragma unroll
        for (int i = 0; i < 4; ++i)
#pragma unroll
            for (int j = 0; j < 4; ++j)
                acc[i][j] = __builtin_amdgcn_mfma_f32_16x16x32_bf16(wf[i], xf[j], acc[i][j], 0, 0, 0);
        // before next iter reads buf[(kt+1)%3]: STAGE(kt+1) (oldest 4) must be done.
        if (kt + 2 < 32) asm volatile("s_waitcnt vmcnt(4) lgkmcnt(0)" ::: "memory");
        else             asm volatile("s_waitcnt vmcnt(0) lgkmcnt(0)" ::: "memory");
        __builtin_amdgcn_s_barrier();
        __builtin_amdgcn_sched_barrier(0);
        cur = (cur == 2) ? 0 : cur + 1;
        stg = (stg == 2) ? 0 : stg + 1;
    }
#undef STAGE

    // epilogue: head-major scatter, 8B vector stores.
    const bool sideK = (n0 >= 1024);
    unsigned short* dst = sideK ? KH : QH;

    int rowoff[4];   // per xrow fragment j (row = lane&15 of D)
#pragma unroll
    for (int j = 0; j < 4; ++j) {
        const int g = m0 + xc + 16 * j + lr;
        const int b = g >> 12, rr = g & 4095;
        int v = -1;
        if (rr >= 2049) {
            const int seg = b * 2 + (sideK ? 0 : 1);
            v = seg * (NH_ * 2048 * 32) + (rr - 2049) * 32;
        } else if (rr >= 1) {
            const int seg = b * 2 + (sideK ? 1 : 0);
            v = seg * (NH_ * 2048 * 32) + (rr - 1) * 32;
        }
        rowoff[j] = v;
    }

    int coloff[4]; f32x4 bias4[4];   // per channel fragment i (4 consec chans)
#pragma unroll
    for (int i = 0; i < 4; ++i) {
        const int c = n0 + cr + 16 * i + lg * 4;
        const int local = c - (sideK ? 1024 : 0);
        coloff[i] = (local >> 5) * (2048 * 32) + (local & 31);
        bias4[i] = *(const f32x4*)&bb[c];
    }

#pragma unroll
    for (int j = 0; j < 4; ++j) {
        if (rowoff[j] < 0) continue;
#pragma unroll
        for (int i = 0; i < 4; ++i) {
            u16x4 o;
#pragma unroll
            for (int r = 0; r < 4; ++r) o[r] = f2bf(acc[i][j][r] + bias4[i][r]);
            *(u16x4*)&dst[(size_t)rowoff[j] + coloff[i]] = o;
        }
    }
}

// ---------------------------------------------------------------------------
// Pass 1: negL[bm][q] = -log2( sum_k exp2(s2[q][k]) ).
// Peeled 2-deep register pipeline, NO conditional loads (round-6 lesson).
// ---------------------------------------------------------------------------
__global__ __launch_bounds__(256) void zpass(const unsigned short* __restrict__ QH,
                                             const unsigned short* __restrict__ KH,
                                             float* __restrict__ NL)
{
    const int tid = threadIdx.x, lane = tid & 63, w = tid >> 6;
    const int bm = blockIdx.z, mha = bm & 1;
    const int h = blockIdx.y;
    const int nq = mha ? NQ2 : NQ1, nk = mha ? NK2 : NK1;
    const size_t panel = ((size_t)bm * NH_ + h) * 2048 * 32;
    const int lr = lane & 15, lg = lane >> 4;
    const int q0 = blockIdx.x * 256 + w * 64;
    const f32x4 zero = {0.f, 0.f, 0.f, 0.f};

    const unsigned short* Qp = QH + panel + (size_t)(q0 + lr) * 32 + lg * 8;
    const unsigned short* Kp = KH + panel + (size_t)lr * 32 + lg * 8;

    bf16x8 a[4];
#pragma unroll
    for (int i = 0; i < 4; ++i) a[i] = *(const bf16x8*)(Qp + i * 16 * 32);

    bf16x8 kb0 = *(const bf16x8*)(Kp);
    bf16x8 kb1 = *(const bf16x8*)(Kp + 512);

    f32x4 z[4] = {zero, zero, zero, zero};
    for (int kt = 0; kt < 126; kt += 2) {
        const bf16x8 n0 = *(const bf16x8*)(Kp + (size_t)(kt + 2) * 512);
        const bf16x8 n1 = *(const bf16x8*)(Kp + (size_t)(kt + 3) * 512);
#pragma unroll
        for (int i = 0; i < 4; ++i) {
            const f32x4 d = __builtin_amdgcn_mfma_f32_16x16x32_bf16(a[i], kb0, zero, 0, 0, 0);
            f32x4 e;
#pragma unroll
            for (int r = 0; r < 4; ++r) e[r] = EXP2(d[r]);
            z[i] += e;
        }
#pragma unroll
        for (int i = 0; i < 4; ++i) {
            const f32x4 d = __builtin_amdgcn_mfma_f32_16x16x32_bf16(a[i], kb1, zero, 0, 0, 0);
            f32x4 e;
#pragma unroll
            for (int r = 0; r < 4; ++r) e[r] = EXP2(d[r]);
            z[i] += e;
        }
        kb0 = n0; kb1 = n1;
    }
    // tile 126 (k = 2016..2031, always unmasked)
#pragma unroll
    for (int i = 0; i < 4; ++i) {
        const f32x4 d = __builtin_amdgcn_mfma_f32_16x16x32_bf16(a[i], kb0, zero, 0, 0, 0);
        f32x4 e;
#pragma unroll
        for (int r = 0; r < 4; ++r) e[r] = EXP2(d[r]);
        z[i] += e;
    }
    {   // tile 127 with column mask (masks pad col 2047 for mha0)
        const float m = (2032 + lr < nk) ? 1.f : 0.f;
#pragma unroll
        for (int i = 0; i < 4; ++i) {
            const f32x4 d = __builtin_amdgcn_mfma_f32_16x16x32_bf16(a[i], kb1, zero, 0, 0, 0);
            f32x4 e;
#pragma unroll
            for (int r = 0; r < 4; ++r) e[r] = m * EXP2(d[r]);
            z[i] += e;
        }
    }

#pragma unroll
    for (int i = 0; i < 4; ++i) {
        f32x4 zi = z[i];
#pragma unroll
        for (int r = 0; r < 4; ++r) {
            float v = zi[r];
            v += __shfl_xor(v, 1, 64);
            v += __shfl_xor(v, 2, 64);
            v += __shfl_xor(v, 4, 64);
            v += __shfl_xor(v, 8, 64);
            zi[r] = v;
        }
        if (lr == 0) {
            const int qb = q0 + i * 16 + lg * 4;
            f32x4 o;
#pragma unroll
            for (int r = 0; r < 4; ++r)
                o[r] = (qb + r < nq) ? -LOG2(zi[r]) : -1e30f;  // -inf masks pad q
            *(f32x4*)&NL[(size_t)bm * 2048 + qb] = o;
        }
    }
}

// ---------------------------------------------------------------------------
// Pass 2: CS[bm][h][k] = sum_q exp2(s2[q][k] + negL[q]).  negL rides in the
// MFMA accumulator. Peeled 2-deep register pipeline, no conditional loads.
// ---------------------------------------------------------------------------
__global__ __launch_bounds__(256) void colsum(const unsigned short* __restrict__ QH,
                                              const unsigned short* __restrict__ KH,
                                              const float* __restrict__ NL,
                                              float* __restrict__ CS)
{
    const int tid = threadIdx.x, lane = tid & 63, w = tid >> 6;
    const int bm = blockIdx.z, mha = bm & 1;
    const int h = blockIdx.y;
    const int nk = mha ? NK2 : NK1;
    const size_t panel = ((size_t)bm * NH_ + h) * 2048 * 32;
    const int lr = lane & 15, lg = lane >> 4;
    const int kc = blockIdx.x * 256 + w * 64;
    const f32x4 zero = {0.f, 0.f, 0.f, 0.f};

    const unsigned short* Kp = KH + panel + (size_t)(kc + lr) * 32 + lg * 8;
    const unsigned short* Qp = QH + panel + (size_t)lr * 32 + lg * 8;
    const float* zp = NL + (size_t)bm * 2048 + lg * 4;

    bf16x8 kb[4];
#pragma unroll
    for (int j = 0; j < 4; ++j) kb[j] = *(const bf16x8*)(Kp + j * 16 * 32);

    bf16x8 ai0 = *(const bf16x8*)(Qp);
    f32x4  cv0 = *(const f32x4*)(zp);
    bf16x8 ai1 = *(const bf16x8*)(Qp + 512);
    f32x4  cv1 = *(const f32x4*)(zp + 16);

    f32x4 cacc[4] = {zero, zero, zero, zero};
    for (int qt = 0; qt < 126; qt += 2) {
        const bf16x8 an0 = *(const bf16x8*)(Qp + (size_t)(qt + 2) * 512);
        const f32x4  cn0 = *(const f32x4*)(zp + (qt + 2) * 16);
        const bf16x8 an1 = *(const bf16x8*)(Qp + (size_t)(qt + 3) * 512);
        const f32x4  cn1 = *(const f32x4*)(zp + (qt + 3) * 16);
#pragma unroll
        for (int j = 0; j < 4; ++j) {
            const f32x4 d = __builtin_amdgcn_mfma_f32_16x16x32_bf16(ai0, kb[j], cv0, 0, 0, 0);
            f32x4 e;
#pragma unroll
            for (int r = 0; r < 4; ++r) e[r] = EXP2(d[r]);
            cacc[j] += e;
        }
#pragma unroll
        for (int j = 0; j < 4; ++j) {
            const f32x4 d = __builtin_amdgcn_mfma_f32_16x16x32_bf16(ai1, kb[j], cv1, 0, 0, 0);
            f32x4 e;
#pragma unroll
            for (int r = 0; r < 4; ++r) e[r] = EXP2(d[r]);
            cacc[j] += e;
        }
        ai0 = an0; cv0 = cn0; ai1 = an1; cv1 = cn1;
    }
    // q-tiles 126, 127 (pad q rows give exp2(-1e30) = 0)
#pragma unroll
    for (int j = 0; j < 4; ++j) {
        const f32x4 d = __builtin_amdgcn_mfma_f32_16x16x32_bf16(ai0, kb[j], cv0, 0, 0, 0);
        f32x4 e;
#pragma unroll
        for (int r = 0; r < 4; ++r) e[r] = EXP2(d[r]);
        cacc[j] += e;
    }
#pragma unroll
    for (int j = 0; j < 4; ++j) {
        const f32x4 d = __builtin_amdgcn_mfma_f32_16x16x32_bf16(ai1, kb[j], cv1, 0, 0, 0);
        f32x4 e;
#pragma unroll
        for (int r = 0; r < 4; ++r) e[r] = EXP2(d[r]);
        cacc[j] += e;
    }

#pragma unroll
    for (int j = 0; j < 4; ++j) {
        float v = (cacc[j][0] + cacc[j][1]) + (cacc[j][2] + cacc[j][3]);
        v += __shfl_xor(v, 16, 64);
        v += __shfl_xor(v, 32, 64);
        const int col = kc + 16 * j + lr;
        if (lane < 16 && col < nk)
            CS[((size_t)bm * NH_ + h) * 2048 + col] = v;
    }
}

// ---------------------------------------------------------------------------
// Pass C stage 1: UP[bm*32+h][kt][c] = sum_{k in tile} CS[bm][h][k]*Xb[k][c]
// grid (kt=16, hg=4, bm=6); NO atomics — pure coalesced stores.
// ---------------------------------------------------------------------------
__global__ __launch_bounds__(256) void colsum_x(
    const unsigned short* __restrict__ Xb, const float* __restrict__ CS,
    float* __restrict__ UP)
{
    __shared__ float sl[8][128];
    const int tid = threadIdx.x;
    const int bm = blockIdx.z;
    const int b = bm >> 1, mha = bm & 1;
    const int kbase = mha ? SEG1 : SEG2;
    const int nk = mha ? NK2 : NK1;
    const int kt = blockIdx.x;           // 0..15, k-tile of 128
    const int k0 = kt * 128;
    const int hg = blockIdx.y * 8;

    for (int idx = tid; idx < 8 * 128; idx += 256) {
        const int hh = idx >> 7, kk = idx & 127;
        const int k = k0 + kk;
        sl[hh][kk] = (k < nk) ? CS[((size_t)bm * NH_ + hg + hh) * 2048 + k] : 0.f;
    }
    __syncthreads();

    float acc[8][4] = {};
    const int c4 = tid * 4;
#pragma unroll 4
    for (int kk = 0; kk < 128; ++kk) {
        const int k = k0 + kk;
        const int krow = (k < nk) ? k : 0;    // sl==0 masks the product
        const u16x4 xv = *(const u16x4*)&Xb[((size_t)b * S_ + kbase + krow) * H_ + c4];
        const float x0 = bf2f(xv[0]), x1 = bf2f(xv[1]), x2 = bf2f(xv[2]), x3 = bf2f(xv[3]);
#pragma unroll
        for (int hh = 0; hh < 8; ++hh) {
            const float sv = sl[hh][kk];
            acc[hh][0] += sv * x0; acc[hh][1] += sv * x1;
            acc[hh][2] += sv * x2; acc[hh][3] += sv * x3;
        }
    }
#pragma unroll
    for (int hh = 0; hh < 8; ++hh) {
        f32x4 o; o[0] = acc[hh][0]; o[1] = acc[hh][1]; o[2] = acc[hh][2]; o[3] = acc[hh][3];
        *(f32x4*)&UP[((size_t)(bm * NH_ + hg + hh) * 16 + kt) * 1024 + c4] = o;
    }
}

// Pass C stage 2: U[row][c] = sum_kt UP[row][kt][c]
__global__ __launch_bounds__(256) void reduce_u(const float* __restrict__ UP,
                                                float* __restrict__ U)
{
    const int gid = blockIdx.x * 256 + threadIdx.x;   // 0..49151
    const int row = gid >> 8;                          // bm*32+h
    const int c4 = (gid & 255) * 4;
    const float* p = UP + (size_t)row * 16 * 1024 + c4;
    f32x4 s = *(const f32x4*)p;
#pragma unroll
    for (int t = 1; t < 16; ++t) s += *(const f32x4*)(p + t * 1024);
    *(f32x4*)&U[(size_t)row * 1024 + c4] = s;
}

// ---------------------------------------------------------------------------
__global__ __launch_bounds__(256) void compute_m(
    const float* __restrict__ U, const float* __restrict__ Wv,
    const float* __restrict__ bv, float* __restrict__ Mvec)
{
    const int bm = blockIdx.y;
    const int mha = bm & 1;
    const float invnq = 1.f / (float)(mha ? NQ2 : NQ1);
    const int o = blockIdx.x * 256 + threadIdx.x;
    const int hh = o >> 5;
    const float* u = &U[((size_t)bm * NH_ + hh) * H_];
    const float* w = &Wv[(size_t)o * H_];
    float acc = 0.f;
    for (int in = 0; in < H_; in += 4) {
        const float4 uv = *(const float4*)&u[in];
        const float4 wv = *(const float4*)&w[in];
        acc += uv.x * wv.x + uv.y * wv.y + uv.z * wv.z + uv.w * wv.w;
    }
    Mvec[(size_t)bm * H_ + o] = acc * invnq + bv[o];
}

__global__ __launch_bounds__(256) void final_out(
    const float* __restrict__ Mvec, const float* __restrict__ Wo,
    const float* __restrict__ bo, float* __restrict__ out)
{
    const int bm = blockIdx.y;
    const int b = bm >> 1, mha = bm & 1;
    const int o = blockIdx.x * 256 + threadIdx.x;
    const float* mv = &Mvec[(size_t)bm * H_];
    const float* w = &Wo[(size_t)o * H_];
    float acc = 0.f;
    for (int in = 0; in < H_; in += 4) {
        const float4 mvv = *(const float4*)&mv[in];
        const float4 wv = *(const float4*)&w[in];
        acc += mvv.x * wv.x + mvv.y * wv.y + mvv.z * wv.z + mvv.w * wv.w;
    }
    out[(size_t)b * 2048 + mha * 1024 + o] = acc + bo[o];
}

// ---------------------------------------------------------------------------
extern "C" void kernel_launch(void* const* d_in, const int* in_sizes, int n_in,
                              void* d_out, int out_size, void* d_ws, size_t ws_size,
                              hipStream_t stream)
{
    const float* hidden = (const float*)d_in[0];
    const float* Wq = (const float*)d_in[7];
    const float* bq = (const float*)d_in[8];
    const float* Wk = (const float*)d_in[9];
    const float* bk = (const float*)d_in[10];
    const float* Wv = (const float*)d_in[11];
    const float* bv = (const float*)d_in[12];
    const float* Wo = (const float*)d_in[13];
    const float* bo = (const float*)d_in[14];
    float* out = (float*)d_out;
    char* ws = (char*)d_ws;

    unsigned short* Xb  = (unsigned short*)(ws + oXb);
    unsigned short* Wb  = (unsigned short*)(ws + oWb);
    float* bb           = (float*)(ws + oBB);
    unsigned short* QHp = (unsigned short*)(ws + oQH);
    unsigned short* KHp = (unsigned short*)(ws + oKH);
    float* NL           = (float*)(ws + oNL);
    float* CS           = (float*)(ws + oCS);
    float* U            = (float*)(ws + oU);
    float* Mv           = (float*)(ws + oMv);
    float* UP           = (float*)(ws + oUP);

    const dim3 blk(256);
    conv_x<<<12288, blk, 0, stream>>>(hidden, Xb);
    conv_w<<<2048, blk, 0, stream>>>(Wq, bq, Wk, bk, Wb, bb, QHp, KHp);
    proj_mfma<<<dim3(96, 16), blk, 0, stream>>>(Xb, Wb, bb, QHp, KHp);
    zpass<<<dim3(8, 32, 6), blk, 0, stream>>>(QHp, KHp, NL);
    colsum<<<dim3(8, 32, 6), blk, 0, stream>>>(QHp, KHp, NL, CS);
    colsum_x<<<dim3(16, 4, 6), blk, 0, stream>>>(Xb, CS, UP);
    reduce_u<<<192, blk, 0, stream>>>(UP, U);
    compute_m<<<dim3(4, 6), blk, 0, stream>>>(U, Wv, bv, Mv);
    final_out<<<dim3(4, 6), blk, 0, stream>>>(Mv, Wo, bo, out);
}

// Round 10
// 377.250 us; speedup vs baseline: 3.6947x; 1.0039x over previous
//
#include <hip/hip_runtime.h>
#include <cstddef>

typedef __attribute__((ext_vector_type(8))) short bf16x8;
typedef __attribute__((ext_vector_type(4))) float f32x4;
typedef __attribute__((ext_vector_type(4))) unsigned short u16x4;
typedef __attribute__((ext_vector_type(8))) unsigned short u16x8;

namespace {
constexpr int B_ = 3, S_ = 4096, H_ = 1024, NH_ = 32;
constexpr int SEG1 = 1, SEG2 = 2049;
constexpr int NQ1 = 2048, NK1 = 2047, NQ2 = 2047, NK2 = 2048;
constexpr float SCALE = 0.17677669529663687f;              // 1/sqrt(32)
constexpr float LOG2E = 1.4426950408889634f;
constexpr float QSC   = SCALE * LOG2E;                     // folded into Wq/bq

// workspace byte offsets (all 16B aligned)
constexpr size_t oXb = 0;                                   // 12288*1024 bf16
constexpr size_t oWb = oXb + (size_t)12288 * 1024 * 2;      // 2048*1024 bf16
constexpr size_t oBB = oWb + (size_t)2048 * 1024 * 2;       // 2048 f32
constexpr size_t oQH = oBB + (size_t)2048 * 4;              // 6*32*2048*32 bf16
constexpr size_t oKH = oQH + (size_t)6 * 32 * 2048 * 32 * 2;
constexpr size_t oNL = oKH + (size_t)6 * 32 * 2048 * 32 * 2;  // negL 6*2048 f32
constexpr size_t oCS = oNL + (size_t)6 * 2048 * 4;          // 6*32*2048 f32
constexpr size_t oU  = oCS + (size_t)6 * 32 * 2048 * 4;     // 6*32*1024 f32
constexpr size_t oMv = oU  + (size_t)6 * 32 * 1024 * 4;     // 6*1024 f32
constexpr size_t oUP = oMv + (size_t)6 * 1024 * 4;          // 192*16*1024 f32 partials
}

#if __has_builtin(__builtin_amdgcn_exp2f)
#define EXP2(x) __builtin_amdgcn_exp2f(x)
#else
#define EXP2(x) exp2f(x)
#endif
#if __has_builtin(__builtin_amdgcn_logf)
#define LOG2(x) __builtin_amdgcn_logf(x)
#else
#define LOG2(x) log2f(x)
#endif

__device__ __forceinline__ unsigned short f2bf(float f) {
    unsigned u = __float_as_uint(f);
    u += 0x7FFF + ((u >> 16) & 1);   // RTNE
    return (unsigned short)(u >> 16);
}
__device__ __forceinline__ float bf2f(unsigned short u) {
    return __uint_as_float((unsigned)u << 16);
}
__device__ __forceinline__ void gl16(const unsigned short* gp, unsigned short* lp) {
    __builtin_amdgcn_global_load_lds(
        (const __attribute__((address_space(1))) unsigned int*)gp,
        (__attribute__((address_space(3))) unsigned int*)lp, 16, 0, 0);
}

// ---------------------------------------------------------------------------
__global__ __launch_bounds__(256) void conv_x(const float* __restrict__ X,
                                              unsigned short* __restrict__ Xb)
{
    const size_t i4 = (size_t)blockIdx.x * 256 + threadIdx.x;
    const float4 v = *(const float4*)&X[i4 * 4];
    u16x4 o;
    o[0] = f2bf(v.x); o[1] = f2bf(v.y); o[2] = f2bf(v.z); o[3] = f2bf(v.w);
    *(u16x4*)&Xb[i4 * 4] = o;
}

// pack [QSC*Wq ; Wk] -> bf16, [QSC*bq ; bk] -> f32; also zero pad rows of QH/KH
__global__ __launch_bounds__(256) void conv_w(const float* __restrict__ Wq,
                                              const float* __restrict__ bq,
                                              const float* __restrict__ Wk,
                                              const float* __restrict__ bk,
                                              unsigned short* __restrict__ Wb,
                                              float* __restrict__ bb,
                                              unsigned short* __restrict__ QH,
                                              unsigned short* __restrict__ KH)
{
    const int i4 = blockIdx.x * 256 + threadIdx.x;
    const int base = i4 * 4;
    const bool isQ = base < (1 << 20);
    const float sc = isQ ? QSC : 1.f;
    const float* src = isQ ? &Wq[base] : &Wk[base - (1 << 20)];
    const float4 v = *(const float4*)src;
    u16x4 o;
    o[0] = f2bf(v.x * sc); o[1] = f2bf(v.y * sc);
    o[2] = f2bf(v.z * sc); o[3] = f2bf(v.w * sc);
    *(u16x4*)&Wb[base] = o;
    if (base < 2048) {
#pragma unroll
        for (int c = 0; c < 4; ++c) {
            const int j = base + c;
            bb[j] = (j < 1024) ? QSC * bq[j] : bk[j - 1024];
        }
    }
    if (i4 < 3072) {   // zero pad rows (idx 2047 of mha1-Q and mha0-K panels)
        const int b = i4 >> 10, rem = i4 & 1023, h = rem >> 5, c = rem & 31;
        QH[(((size_t)(b * 2 + 1) * NH_ + h) * 2048 + 2047) * 32 + c] = 0;
        KH[(((size_t)(b * 2 + 0) * NH_ + h) * 2048 + 2047) * 32 + c] = 0;
    }
}

// ---------------------------------------------------------------------------
// Fused Q|K projection -> head-major scatter.  A-operand = W, B-operand = X.
// 3-buffer LDS pipeline, counted vmcnt(4); no sched_barrier pins (let the
// scheduler overlap; inline-asm "memory" clobbers already order LDS ops).
// ---------------------------------------------------------------------------
__global__ __launch_bounds__(256) void proj_mfma(const unsigned short* __restrict__ Xb,
                                                 const unsigned short* __restrict__ Wb,
                                                 const float* __restrict__ bb,
                                                 unsigned short* __restrict__ QH,
                                                 unsigned short* __restrict__ KH)
{
    __shared__ unsigned short ldsX[3 * 4096];   // [buf][128 rows * 32 (=BK)]
    __shared__ unsigned short ldsW[3 * 4096];
    const int tid = threadIdx.x;
    const int lane = tid & 63, w = tid >> 6;
    const int m0 = blockIdx.x * 128;   // x-rows
    const int n0 = blockIdx.y * 128;   // output channels (Q: 0..1023, K: 1024..2047)
    const int cr = (w >> 1) * 64;      // channel half owned by this wave
    const int xc = (w & 1) * 64;       // xrow half owned by this wave

    // staging: lane -> row (lane>>2), granule pre-swizzled g ^ ((row>>1)&3)
    const int co = ((lane & 3) ^ ((lane >> 3) & 3)) * 8;
    const unsigned short* gX = Xb + (size_t)(m0 + 32 * w + (lane >> 2)) * 1024 + co;
    const unsigned short* gW = Wb + (size_t)(n0 + 32 * w + (lane >> 2)) * 1024 + co;

#define STAGE(K0, BUF) do { \
    gl16(gX + (K0),             &ldsX[(BUF) * 4096 + (32 * w) * 32]); \
    gl16(gX + (K0) + 16 * 1024, &ldsX[(BUF) * 4096 + (32 * w + 16) * 32]); \
    gl16(gW + (K0),             &ldsW[(BUF) * 4096 + (32 * w) * 32]); \
    gl16(gW + (K0) + 16 * 1024, &ldsW[(BUF) * 4096 + (32 * w + 16) * 32]); \
} while (0)

    // fragment read offsets (same XOR on the read side; row+16 keeps same XOR)
    const int lr = lane & 15, lg = lane >> 4;
    const int mrW = cr + lr, mrX = xc + lr;
    const int oW = mrW * 32 + ((lg ^ ((mrW >> 1) & 3)) * 8);
    const int oX = mrX * 32 + ((lg ^ ((mrX >> 1) & 3)) * 8);

    f32x4 acc[4][4] = {};
    STAGE(0, 0);
    STAGE(32, 1);
    asm volatile("s_waitcnt vmcnt(4)" ::: "memory");   // STAGE(0) landed
    __builtin_amdgcn_s_barrier();

    int cur = 0, stg = 2;
    for (int kt = 0; kt < 32; ++kt) {
        const int cb = cur * 4096;
        bf16x8 wf[4], xf[4];
#pragma unroll
        for (int i = 0; i < 4; ++i) wf[i] = *(const bf16x8*)&ldsW[cb + oW + i * 512];
#pragma unroll
        for (int j = 0; j < 4; ++j) xf[j] = *(const bf16x8*)&ldsX[cb + oX + j * 512];
        if (kt + 2 < 32) STAGE((kt + 2) * 32, stg);
#pragma unroll
        for (int i = 0; i < 4; ++i)
#pragma unroll
            for (int j = 0; j < 4; ++j)
                acc[i][j] = __builtin_amdgcn_mfma_f32_16x16x32_bf16(wf[i], xf[j], acc[i][j], 0, 0, 0);
        // before next iter reads buf[(kt+1)%3]: STAGE(kt+1) (oldest 4) must be done.
        if (kt + 2 < 32) asm volatile("s_waitcnt vmcnt(4) lgkmcnt(0)" ::: "memory");
        else             asm volatile("s_waitcnt vmcnt(0) lgkmcnt(0)" ::: "memory");
        __builtin_amdgcn_s_barrier();
        cur = (cur == 2) ? 0 : cur + 1;
        stg = (stg == 2) ? 0 : stg + 1;
    }
#undef STAGE

    // epilogue: head-major scatter, 8B vector stores.
    const bool sideK = (n0 >= 1024);
    unsigned short* dst = sideK ? KH : QH;

    int rowoff[4];   // per xrow fragment j (row = lane&15 of D)
#pragma unroll
    for (int j = 0; j < 4; ++j) {
        const int g = m0 + xc + 16 * j + lr;
        const int b = g >> 12, rr = g & 4095;
        int v = -1;
        if (rr >= 2049) {
            const int seg = b * 2 + (sideK ? 0 : 1);
            v = seg * (NH_ * 2048 * 32) + (rr - 2049) * 32;
        } else if (rr >= 1) {
            const int seg = b * 2 + (sideK ? 1 : 0);
            v = seg * (NH_ * 2048 * 32) + (rr - 1) * 32;
        }
        rowoff[j] = v;
    }

    int coloff[4]; f32x4 bias4[4];   // per channel fragment i (4 consec chans)
#pragma unroll
    for (int i = 0; i < 4; ++i) {
        const int c = n0 + cr + 16 * i + lg * 4;
        const int local = c - (sideK ? 1024 : 0);
        coloff[i] = (local >> 5) * (2048 * 32) + (local & 31);
        bias4[i] = *(const f32x4*)&bb[c];
    }

#pragma unroll
    for (int j = 0; j < 4; ++j) {
        if (rowoff[j] < 0) continue;
#pragma unroll
        for (int i = 0; i < 4; ++i) {
            u16x4 o;
#pragma unroll
            for (int r = 0; r < 4; ++r) o[r] = f2bf(acc[i][j][r] + bias4[i][r]);
            *(u16x4*)&dst[(size_t)rowoff[j] + coloff[i]] = o;
        }
    }
}

// ---------------------------------------------------------------------------
// Pass 1: negL[bm][q] = -log2( sum_k exp2(s2[q][k]) ).
// grid (192 panels, 8 qtiles): panel is the FAST grid index so the 8 q-tiles
// sharing one K-panel land on the SAME XCD (192%8==0) -> K panel L2-resident.
// Peeled 2-deep register pipeline, no conditional loads.
// ---------------------------------------------------------------------------
__global__ __launch_bounds__(256) void zpass(const unsigned short* __restrict__ QH,
                                             const unsigned short* __restrict__ KH,
                                             float* __restrict__ NL)
{
    const int tid = threadIdx.x, lane = tid & 63, w = tid >> 6;
    const int pan = blockIdx.x;            // bm*NH + h
    const int bm = pan >> 5, mha = bm & 1;
    const int nq = mha ? NQ2 : NQ1, nk = mha ? NK2 : NK1;
    const size_t panel = (size_t)pan * 2048 * 32;
    const int lr = lane & 15, lg = lane >> 4;
    const int q0 = blockIdx.y * 256 + w * 64;
    const f32x4 zero = {0.f, 0.f, 0.f, 0.f};

    const unsigned short* Qp = QH + panel + (size_t)(q0 + lr) * 32 + lg * 8;
    const unsigned short* Kp = KH + panel + (size_t)lr * 32 + lg * 8;

    bf16x8 a[4];
#pragma unroll
    for (int i = 0; i < 4; ++i) a[i] = *(const bf16x8*)(Qp + i * 16 * 32);

    bf16x8 kb0 = *(const bf16x8*)(Kp);
    bf16x8 kb1 = *(const bf16x8*)(Kp + 512);

    f32x4 z[4] = {zero, zero, zero, zero};
    for (int kt = 0; kt < 126; kt += 2) {
        const bf16x8 n0 = *(const bf16x8*)(Kp + (size_t)(kt + 2) * 512);
        const bf16x8 n1 = *(const bf16x8*)(Kp + (size_t)(kt + 3) * 512);
#pragma unroll
        for (int i = 0; i < 4; ++i) {
            const f32x4 d = __builtin_amdgcn_mfma_f32_16x16x32_bf16(a[i], kb0, zero, 0, 0, 0);
            f32x4 e;
#pragma unroll
            for (int r = 0; r < 4; ++r) e[r] = EXP2(d[r]);
            z[i] += e;
        }
#pragma unroll
        for (int i = 0; i < 4; ++i) {
            const f32x4 d = __builtin_amdgcn_mfma_f32_16x16x32_bf16(a[i], kb1, zero, 0, 0, 0);
            f32x4 e;
#pragma unroll
            for (int r = 0; r < 4; ++r) e[r] = EXP2(d[r]);
            z[i] += e;
        }
        kb0 = n0; kb1 = n1;
    }
    // tile 126 (k = 2016..2031, always unmasked)
#pragma unroll
    for (int i = 0; i < 4; ++i) {
        const f32x4 d = __builtin_amdgcn_mfma_f32_16x16x32_bf16(a[i], kb0, zero, 0, 0, 0);
        f32x4 e;
#pragma unroll
        for (int r = 0; r < 4; ++r) e[r] = EXP2(d[r]);
        z[i] += e;
    }
    {   // tile 127 with column mask (masks pad col 2047 for mha0)
        const float m = (2032 + lr < nk) ? 1.f : 0.f;
#pragma unroll
        for (int i = 0; i < 4; ++i) {
            const f32x4 d = __builtin_amdgcn_mfma_f32_16x16x32_bf16(a[i], kb1, zero, 0, 0, 0);
            f32x4 e;
#pragma unroll
            for (int r = 0; r < 4; ++r) e[r] = m * EXP2(d[r]);
            z[i] += e;
        }
    }

#pragma unroll
    for (int i = 0; i < 4; ++i) {
        f32x4 zi = z[i];
#pragma unroll
        for (int r = 0; r < 4; ++r) {
            float v = zi[r];
            v += __shfl_xor(v, 1, 64);
            v += __shfl_xor(v, 2, 64);
            v += __shfl_xor(v, 4, 64);
            v += __shfl_xor(v, 8, 64);
            zi[r] = v;
        }
        if (lr == 0) {
            const int qb = q0 + i * 16 + lg * 4;
            f32x4 o;
#pragma unroll
            for (int r = 0; r < 4; ++r)
                o[r] = (qb + r < nq) ? -LOG2(zi[r]) : -1e30f;  // -inf masks pad q
            *(f32x4*)&NL[(size_t)bm * 2048 + qb] = o;
        }
    }
}

// ---------------------------------------------------------------------------
// Pass 2: CS[bm][h][k] = sum_q exp2(s2[q][k] + negL[q]).  negL rides in the
// MFMA accumulator. grid (192 panels, 8 ktiles) — panel-major for XCD/L2
// locality. Peeled 2-deep register pipeline.
// ---------------------------------------------------------------------------
__global__ __launch_bounds__(256) void colsum(const unsigned short* __restrict__ QH,
                                              const unsigned short* __restrict__ KH,
                                              const float* __restrict__ NL,
                                              float* __restrict__ CS)
{
    const int tid = threadIdx.x, lane = tid & 63, w = tid >> 6;
    const int pan = blockIdx.x;            // bm*NH + h
    const int bm = pan >> 5, mha = bm & 1;
    const int nk = mha ? NK2 : NK1;
    const size_t panel = (size_t)pan * 2048 * 32;
    const int lr = lane & 15, lg = lane >> 4;
    const int kc = blockIdx.y * 256 + w * 64;
    const f32x4 zero = {0.f, 0.f, 0.f, 0.f};

    const unsigned short* Kp = KH + panel + (size_t)(kc + lr) * 32 + lg * 8;
    const unsigned short* Qp = QH + panel + (size_t)lr * 32 + lg * 8;
    const float* zp = NL + (size_t)bm * 2048 + lg * 4;

    bf16x8 kb[4];
#pragma unroll
    for (int j = 0; j < 4; ++j) kb[j] = *(const bf16x8*)(Kp + j * 16 * 32);

    bf16x8 ai0 = *(const bf16x8*)(Qp);
    f32x4  cv0 = *(const f32x4*)(zp);
    bf16x8 ai1 = *(const bf16x8*)(Qp + 512);
    f32x4  cv1 = *(const f32x4*)(zp + 16);

    f32x4 cacc[4] = {zero, zero, zero, zero};
    for (int qt = 0; qt < 126; qt += 2) {
        const bf16x8 an0 = *(const bf16x8*)(Qp + (size_t)(qt + 2) * 512);
        const f32x4  cn0 = *(const f32x4*)(zp + (qt + 2) * 16);
        const bf16x8 an1 = *(const bf16x8*)(Qp + (size_t)(qt + 3) * 512);
        const f32x4  cn1 = *(const f32x4*)(zp + (qt + 3) * 16);
#pragma unroll
        for (int j = 0; j < 4; ++j) {
            const f32x4 d = __builtin_amdgcn_mfma_f32_16x16x32_bf16(ai0, kb[j], cv0, 0, 0, 0);
            f32x4 e;
#pragma unroll
            for (int r = 0; r < 4; ++r) e[r] = EXP2(d[r]);
            cacc[j] += e;
        }
#pragma unroll
        for (int j = 0; j < 4; ++j) {
            const f32x4 d = __builtin_amdgcn_mfma_f32_16x16x32_bf16(ai1, kb[j], cv1, 0, 0, 0);
            f32x4 e;
#pragma unroll
            for (int r = 0; r < 4; ++r) e[r] = EXP2(d[r]);
            cacc[j] += e;
        }
        ai0 = an0; cv0 = cn0; ai1 = an1; cv1 = cn1;
    }
    // q-tiles 126, 127 (pad q rows give exp2(-1e30) = 0)
#pragma unroll
    for (int j = 0; j < 4; ++j) {
        const f32x4 d = __builtin_amdgcn_mfma_f32_16x16x32_bf16(ai0, kb[j], cv0, 0, 0, 0);
        f32x4 e;
#pragma unroll
        for (int r = 0; r < 4; ++r) e[r] = EXP2(d[r]);
        cacc[j] += e;
    }
#pragma unroll
    for (int j = 0; j < 4; ++j) {
        const f32x4 d = __builtin_amdgcn_mfma_f32_16x16x32_bf16(ai1, kb[j], cv1, 0, 0, 0);
        f32x4 e;
#pragma unroll
        for (int r = 0; r < 4; ++r) e[r] = EXP2(d[r]);
        cacc[j] += e;
    }

#pragma unroll
    for (int j = 0; j < 4; ++j) {
        float v = (cacc[j][0] + cacc[j][1]) + (cacc[j][2] + cacc[j][3]);
        v += __shfl_xor(v, 16, 64);
        v += __shfl_xor(v, 32, 64);
        const int col = kc + 16 * j + lr;
        if (lane < 16 && col < nk)
            CS[(size_t)pan * 2048 + col] = v;
    }
}

// ---------------------------------------------------------------------------
// Pass C stage 1: UP[bm*32+h][kt][c] = sum_{k in tile} CS[bm][h][k]*Xb[k][c]
// grid (kt=16, hg=4, bm=6); NO atomics — pure coalesced stores.
// ---------------------------------------------------------------------------
__global__ __launch_bounds__(256) void colsum_x(
    const unsigned short* __restrict__ Xb, const float* __restrict__ CS,
    float* __restrict__ UP)
{
    __shared__ float sl[8][128];
    const int tid = threadIdx.x;
    const int bm = blockIdx.z;
    const int b = bm >> 1, mha = bm & 1;
    const int kbase = mha ? SEG1 : SEG2;
    const int nk = mha ? NK2 : NK1;
    const int kt = blockIdx.x;           // 0..15, k-tile of 128
    const int k0 = kt * 128;
    const int hg = blockIdx.y * 8;

    for (int idx = tid; idx < 8 * 128; idx += 256) {
        const int hh = idx >> 7, kk = idx & 127;
        const int k = k0 + kk;
        sl[hh][kk] = (k < nk) ? CS[((size_t)bm * NH_ + hg + hh) * 2048 + k] : 0.f;
    }
    __syncthreads();

    float acc[8][4] = {};
    const int c4 = tid * 4;
#pragma unroll 4
    for (int kk = 0; kk < 128; ++kk) {
        const int k = k0 + kk;
        const int krow = (k < nk) ? k : 0;    // sl==0 masks the product
        const u16x4 xv = *(const u16x4*)&Xb[((size_t)b * S_ + kbase + krow) * H_ + c4];
        const float x0 = bf2f(xv[0]), x1 = bf2f(xv[1]), x2 = bf2f(xv[2]), x3 = bf2f(xv[3]);
#pragma unroll
        for (int hh = 0; hh < 8; ++hh) {
            const float sv = sl[hh][kk];
            acc[hh][0] += sv * x0; acc[hh][1] += sv * x1;
            acc[hh][2] += sv * x2; acc[hh][3] += sv * x3;
        }
    }
#pragma unroll
    for (int hh = 0; hh < 8; ++hh) {
        f32x4 o; o[0] = acc[hh][0]; o[1] = acc[hh][1]; o[2] = acc[hh][2]; o[3] = acc[hh][3];
        *(f32x4*)&UP[((size_t)(bm * NH_ + hg + hh) * 16 + kt) * 1024 + c4] = o;
    }
}

// Pass C stage 2: U[row][c] = sum_kt UP[row][kt][c]
__global__ __launch_bounds__(256) void reduce_u(const float* __restrict__ UP,
                                                float* __restrict__ U)
{
    const int gid = blockIdx.x * 256 + threadIdx.x;   // 0..49151
    const int row = gid >> 8;                          // bm*32+h
    const int c4 = (gid & 255) * 4;
    const float* p = UP + (size_t)row * 16 * 1024 + c4;
    f32x4 s = *(const f32x4*)p;
#pragma unroll
    for (int t = 1; t < 16; ++t) s += *(const f32x4*)(p + t * 1024);
    *(f32x4*)&U[(size_t)row * 1024 + c4] = s;
}

// ---------------------------------------------------------------------------
__global__ __launch_bounds__(256) void compute_m(
    const float* __restrict__ U, const float* __restrict__ Wv,
    const float* __restrict__ bv, float* __restrict__ Mvec)
{
    const int bm = blockIdx.y;
    const int mha = bm & 1;
    const float invnq = 1.f / (float)(mha ? NQ2 : NQ1);
    const int o = blockIdx.x * 256 + threadIdx.x;
    const int hh = o >> 5;
    const float* u = &U[((size_t)bm * NH_ + hh) * H_];
    const float* w = &Wv[(size_t)o * H_];
    float acc = 0.f;
    for (int in = 0; in < H_; in += 4) {
        const float4 uv = *(const float4*)&u[in];
        const float4 wv = *(const float4*)&w[in];
        acc += uv.x * wv.x + uv.y * wv.y + uv.z * wv.z + uv.w * wv.w;
    }
    Mvec[(size_t)bm * H_ + o] = acc * invnq + bv[o];
}

__global__ __launch_bounds__(256) void final_out(
    const float* __restrict__ Mvec, const float* __restrict__ Wo,
    const float* __restrict__ bo, float* __restrict__ out)
{
    const int bm = blockIdx.y;
    const int b = bm >> 1, mha = bm & 1;
    const int o = blockIdx.x * 256 + threadIdx.x;
    const float* mv = &Mvec[(size_t)bm * H_];
    const float* w = &Wo[(size_t)o * H_];
    float acc = 0.f;
    for (int in = 0; in < H_; in += 4) {
        const float4 mvv = *(const float4*)&mv[in];
        const float4 wv = *(const float4*)&w[in];
        acc += mvv.x * wv.x + mvv.y * wv.y + mvv.z * wv.z + mvv.w * wv.w;
    }
    out[(size_t)b * 2048 + mha * 1024 + o] = acc + bo[o];
}

// ---------------------------------------------------------------------------
extern "C" void kernel_launch(void* const* d_in, const int* in_sizes, int n_in,
                              void* d_out, int out_size, void* d_ws, size_t ws_size,
                              hipStream_t stream)
{
    const float* hidden = (const float*)d_in[0];
    const float* Wq = (const float*)d_in[7];
    const float* bq = (const float*)d_in[8];
    const float* Wk = (const float*)d_in[9];
    const float* bk = (const float*)d_in[10];
    const float* Wv = (const float*)d_in[11];
    const float* bv = (const float*)d_in[12];
    const float* Wo = (const float*)d_in[13];
    const float* bo = (const float*)d_in[14];
    float* out = (float*)d_out;
    char* ws = (char*)d_ws;

    unsigned short* Xb  = (unsigned short*)(ws + oXb);
    unsigned short* Wb  = (unsigned short*)(ws + oWb);
    float* bb           = (float*)(ws + oBB);
    unsigned short* QHp = (unsigned short*)(ws + oQH);
    unsigned short* KHp = (unsigned short*)(ws + oKH);
    float* NL           = (float*)(ws + oNL);
    float* CS           = (float*)(ws + oCS);
    float* U            = (float*)(ws + oU);
    float* Mv           = (float*)(ws + oMv);
    float* UP           = (float*)(ws + oUP);

    const dim3 blk(256);
    conv_x<<<12288, blk, 0, stream>>>(hidden, Xb);
    conv_w<<<2048, blk, 0, stream>>>(Wq, bq, Wk, bk, Wb, bb, QHp, KHp);
    proj_mfma<<<dim3(96, 16), blk, 0, stream>>>(Xb, Wb, bb, QHp, KHp);
    zpass<<<dim3(192, 8), blk, 0, stream>>>(QHp, KHp, NL);
    colsum<<<dim3(192, 8), blk, 0, stream>>>(QHp, KHp, NL, CS);
    colsum_x<<<dim3(16, 4, 6), blk, 0, stream>>>(Xb, CS, UP);
    reduce_u<<<192, blk, 0, stream>>>(UP, U);
    compute_m<<<dim3(4, 6), blk, 0, stream>>>(U, Wv, bv, Mv);
    final_out<<<dim3(4, 6), blk, 0, stream>>>(Mv, Wo, bo, out);
}